// Round 17
// baseline (1251.655 us; speedup 1.0000x reference)
//
#include <hip/hip_runtime.h>
#include <hip/hip_bf16.h>

// SymGAT fused layer. Round 17: k_edge stages e as fp16 in LDS.
//  - Els[64][136] fp16 = 17.4KB (was 33.8KB fp32) -> 8 blocks/CU (~100% occ,
//    was 44%). A-fragments read directly as f16x8 (identical values; the
//    fp32->fp16 conversion moves to staging). Residual uses fp16(e): error
//    ~2^-11 relative, negligible vs the 0.0625 baseline absmax.
//  - everything else identical to round-16 passing baseline (1243us).

typedef _Float16 f16x8 __attribute__((ext_vector_type(8)));
typedef _Float16 f16x4 __attribute__((ext_vector_type(4)));
typedef float f32x4 __attribute__((ext_vector_type(4)));

__device__ inline float lrelu(float x) { return x > 0.f ? x : 0.01f * x; }

__device__ inline unsigned short f2bf(float f) {  // RNE float->bf16
  unsigned u = __float_as_uint(f);
  unsigned r = (u + 0x7FFFu + ((u >> 16) & 1u)) >> 16;
  return (unsigned short)r;
}
__device__ inline float bf2f(unsigned short us) {
  return __uint_as_float(((unsigned)us) << 16);
}

// ---------------- K0: weight combos ----------------
__global__ void k_combine(const float* __restrict__ Wfc, const float* __restrict__ Wfce,
                          const float* __restrict__ Wmix, const float* __restrict__ aat,
                          const float* __restrict__ aate, float* __restrict__ Mc,
                          float* __restrict__ cvec) {
  int b = blockIdx.x, j = threadIdx.x;
  if (b < 256) {
    const float* Arow;
    const float* Wm;
    if (b < 128) { Arow = Wfc + b * 128; Wm = Wmix; }
    else         { Arow = Wfce + (b - 128) * 128; Wm = Wmix + 128 * 128; }
    float acc = 0.f;
    for (int t = 0; t < 128; ++t) acc += Arow[t] * Wm[t * 128 + j];
    Mc[b * 128 + j] = acc;
  } else {
    int idx = b - 256;
    const float* W; const float* a;
    switch (idx) {
      case 0: W = Wfc;  a = aat;        break;  // c_s1 @ cvec+0
      case 1: W = Wfce; a = aat + 128;  break;  // c_s2 @ cvec+128
      case 2: W = Wfc;  a = aat + 256;  break;  // c_s3 @ cvec+256
      case 3: W = Wfc;  a = aate;       break;  // c_e1 @ cvec+384
      case 4: W = Wfce; a = aate + 128; break;  // c_e2 @ cvec+512
      default: W = Wfc; a = aate + 256; break;  // c_e3 @ cvec+640
    }
    float acc = 0.f;
    for (int t = 0; t < 128; ++t) acc += W[j * 128 + t] * a[t];
    cvec[idx * 128 + j] = acc;
  }
}

// ---------------- WT3: {W_B3, W_B1, W_B2} -> fp16 transposed ----------------
__global__ __launch_bounds__(256) void k_wt3(const float* __restrict__ W3,
                                             const float* __restrict__ W1,
                                             const float* __restrict__ W2,
                                             _Float16* __restrict__ WT,
                                             _Float16* __restrict__ W1T,
                                             _Float16* __restrict__ W2T) {
  int idx = blockIdx.x * 256 + threadIdx.x;  // 49152 total
  int which = idx >> 14;
  int r = idx & 16383;
  int c = r >> 7, k = r & 127;
  const float* s = (which == 0) ? W3 : (which == 1) ? W1 : W2;
  _Float16* d = (which == 0) ? WT : (which == 1) ? W1T : W2T;
  d[r] = (_Float16)s[k * 128 + c];
}

// ---------------- McT: Mc[256][128] -> fp16 transposed [128][256] ----------------
__global__ __launch_bounds__(256) void k_mcT(const float* __restrict__ Mc,
                                             _Float16* __restrict__ McT) {
  int idx = blockIdx.x * 256 + threadIdx.x;  // 32768 total
  int c = idx >> 8, k = idx & 255;
  McT[idx] = (_Float16)Mc[k * 128 + c];
}

// ---------------- K1: dual GEMM (fp16 MFMA) + nodevec dots + hh shadow ----------------
__global__ __launch_bounds__(256) void k_gemm_dual(const float* __restrict__ A,
                                                   const _Float16* __restrict__ W1T,
                                                   const float* __restrict__ b1v,
                                                   const _Float16* __restrict__ W2T,
                                                   const float* __restrict__ b2v,
                                                   const float* __restrict__ cvec,
                                                   float* __restrict__ out1,
                                                   float* __restrict__ out2,
                                                   unsigned short* __restrict__ hh,
                                                   float* __restrict__ zs1, float* __restrict__ zs3,
                                                   float* __restrict__ ze1, float* __restrict__ ze3,
                                                   int M) {
  __shared__ float Als[64][132];
  int tid = threadIdx.x;
  int lane = tid & 63, w = tid >> 6;
  int kgrp = lane >> 4, sub = lane & 15;
  long mbase = (long)blockIdx.x * 64;
#pragma unroll
  for (int it = 0; it < 8; ++it) {
    int idx = tid + it * 256;
    int r = idx >> 5, cv = idx & 31;
    long m = mbase + r;
    float4 v = make_float4(0.f, 0.f, 0.f, 0.f);
    if (m < M) v = *(const float4*)&A[m * 128 + 4 * cv];
    *(float4*)&Als[r][4 * cv] = v;
  }
  __syncthreads();

  int arow = w * 16 + sub;
  f16x8 afr[4];
#pragma unroll
  for (int ks = 0; ks < 4; ++ks) {
    float4 u0 = *(const float4*)&Als[arow][ks * 32 + kgrp * 8];
    float4 u1 = *(const float4*)&Als[arow][ks * 32 + kgrp * 8 + 4];
    f16x8 a;
    a[0] = (_Float16)u0.x; a[1] = (_Float16)u0.y; a[2] = (_Float16)u0.z; a[3] = (_Float16)u0.w;
    a[4] = (_Float16)u1.x; a[5] = (_Float16)u1.y; a[6] = (_Float16)u1.z; a[7] = (_Float16)u1.w;
    afr[ks] = a;
  }

  f32x4 acc1[8], acc2[8];
#pragma unroll
  for (int t = 0; t < 8; ++t) {
    acc1[t] = (f32x4){0.f, 0.f, 0.f, 0.f};
    acc2[t] = (f32x4){0.f, 0.f, 0.f, 0.f};
  }
#pragma unroll
  for (int ks = 0; ks < 4; ++ks)
#pragma unroll
    for (int t = 0; t < 8; ++t) {
      int boff = (t * 16 + sub) * 128 + ks * 32 + kgrp * 8;
      f16x8 b1 = *(const f16x8*)&W1T[boff];
      acc1[t] = __builtin_amdgcn_mfma_f32_16x16x32_f16(afr[ks], b1, acc1[t], 0, 0, 0);
      f16x8 b2 = *(const f16x8*)&W2T[boff];
      acc2[t] = __builtin_amdgcn_mfma_f32_16x16x32_f16(afr[ks], b2, acc2[t], 0, 0, 0);
    }

  float bb1[8], bb2[8];
#pragma unroll
  for (int t = 0; t < 8; ++t) {
    int c = t * 16 + sub;
    bb1[t] = b1v[c];
    bb2[t] = b2v[c];
  }

  // epilogue in MFMA lane layout; z-dots and hh from EXACT fp32 h in Als
#pragma unroll
  for (int r = 0; r < 4; ++r) {
    int rl = w * 16 + kgrp * 4 + r;
    long m = mbase + rl;
    float p1 = 0.f, p3 = 0.f, q1 = 0.f, q3 = 0.f;
    if (m < M) {
#pragma unroll
      for (int t = 0; t < 8; ++t) {
        int c = t * 16 + sub;
        float a = Als[rl][c];
        out1[m * 128 + c] = acc1[t][r] + bb1[t];
        out2[m * 128 + c] = acc2[t][r] + bb2[t];
        hh[m * 128 + c] = f2bf(a);
        p1 += a * cvec[c];
        p3 += a * cvec[256 + c];
        q1 += a * cvec[384 + c];
        q3 += a * cvec[640 + c];
      }
    }
#pragma unroll
    for (int mk = 1; mk < 16; mk <<= 1) {
      p1 += __shfl_xor(p1, mk); p3 += __shfl_xor(p3, mk);
      q1 += __shfl_xor(q1, mk); q3 += __shfl_xor(q3, mk);
    }
    if (m < M && sub == 0) { zs1[m] = p1; zs3[m] = p3; ze1[m] = q1; ze3[m] = q3; }
  }
}

// ---------------- K2: fused edge kernel (fp16 MFMA, fp16 LDS -> 8 blocks/CU) ----------------
__global__ __launch_bounds__(256) void k_edge(const float* __restrict__ e,
                                              const _Float16* __restrict__ WT,
                                              const float* __restrict__ bias,
                                              const float* __restrict__ B1h,
                                              const float* __restrict__ B2h,
                                              const int* __restrict__ src, const int* __restrict__ dst,
                                              const float* __restrict__ cs2, const float* __restrict__ ce2,
                                              float* __restrict__ eout, unsigned short* __restrict__ ejh,
                                              float* __restrict__ zs2, float* __restrict__ ze2, int M) {
  __shared__ _Float16 Els[64][136];  // 17.4KB; row stride 272B = 68 dwords % 32 = 4
  int tid = threadIdx.x;
  int lane = tid & 63, w = tid >> 6;
  int kgrp = lane >> 4, sub = lane & 15;
  long mbase = (long)blockIdx.x * 64;
#pragma unroll
  for (int it = 0; it < 8; ++it) {
    int idx = tid + it * 256;
    int r = idx >> 5, cv = idx & 31;
    long m = mbase + r;
    float4 v = make_float4(0.f, 0.f, 0.f, 0.f);
    if (m < M) v = *(const float4*)&e[m * 128 + 4 * cv];
    f16x4 hv;
    hv[0] = (_Float16)v.x; hv[1] = (_Float16)v.y;
    hv[2] = (_Float16)v.z; hv[3] = (_Float16)v.w;
    *(f16x4*)&Els[r][4 * cv] = hv;
  }
  __syncthreads();

  int arow = w * 16 + sub;
  f16x8 afr[4];
#pragma unroll
  for (int ks = 0; ks < 4; ++ks)
    afr[ks] = *(const f16x8*)&Els[arow][ks * 32 + kgrp * 8];

  f32x4 acc[8];
#pragma unroll
  for (int t = 0; t < 8; ++t) acc[t] = (f32x4){0.f, 0.f, 0.f, 0.f};
#pragma unroll
  for (int ks = 0; ks < 4; ++ks)
#pragma unroll
    for (int t = 0; t < 8; ++t) {
      f16x8 b = *(const f16x8*)&WT[(t * 16 + sub) * 128 + ks * 32 + kgrp * 8];
      acc[t] = __builtin_amdgcn_mfma_f32_16x16x32_f16(afr[ks], b, acc[t], 0, 0, 0);
    }

  float bb[8], cs[8], ce[8];
#pragma unroll
  for (int t = 0; t < 8; ++t) {
    int c = t * 16 + sub;
    bb[t] = bias[c];
    cs[t] = cs2[c];
    ce[t] = ce2[c];
  }

  // epilogue in MFMA lane layout: lane owns rows w*16+kgrp*4+r, cols t*16+sub
#pragma unroll
  for (int r = 0; r < 4; ++r) {
    int rl = w * 16 + kgrp * 4 + r;
    long m = mbase + rl;
    float ps = 0.f, pe = 0.f;
    if (m < M) {
      int s = src[m], dv = dst[m];
      const float* b1p = B1h + (long)s * 128;
      const float* b2p = B2h + (long)dv * 128;
#pragma unroll
      for (int t = 0; t < 8; ++t) {
        int c = t * 16 + sub;
        float o = fmaxf(acc[t][r] + bb[t] + b1p[c] + b2p[c], 0.f) + (float)Els[rl][c];
        eout[m * 128 + c] = o;
        ejh[m * 128 + c] = f2bf(o);
        ps += o * cs[t];
        pe += o * ce[t];
      }
    }
#pragma unroll
    for (int mk = 1; mk < 16; mk <<= 1) {
      ps += __shfl_xor(ps, mk);
      pe += __shfl_xor(pe, mk);
    }
    if (m < M && sub == 0) { zs2[m] = ps; ze2[m] = pe; }
  }
}

// ---------------- CSR build ----------------
__global__ void k_hist(const int* __restrict__ src, const int* __restrict__ dst,
                       int* __restrict__ cntf, int* __restrict__ cntr, int E) {
  int e = blockIdx.x * 256 + threadIdx.x;
  if (e < E) {
    atomicAdd(&cntf[dst[e]], 1);
    atomicAdd(&cntr[src[e]], 1);
  }
}

__global__ __launch_bounds__(1024) void k_scan(const int* __restrict__ cntf,
                                               const int* __restrict__ cntr,
                                               int* __restrict__ offf, int* __restrict__ offr, int n) {
  __shared__ int part[1024];
  int tid = threadIdx.x;
  for (int pass = 0; pass < 2; ++pass) {
    const int* cnt = pass ? cntr : cntf;
    int* off = pass ? offr : offf;
    int per = (n + 1023) >> 10;
    int beg = tid * per; if (beg > n) beg = n;
    int end = beg + per; if (end > n) end = n;
    int s = 0;
    for (int i = beg; i < end; ++i) s += cnt[i];
    part[tid] = s;
    __syncthreads();
    for (int o = 1; o < 1024; o <<= 1) {
      int vv = (tid >= o) ? part[tid - o] : 0;
      __syncthreads();
      part[tid] += vv;
      __syncthreads();
    }
    int run = tid ? part[tid - 1] : 0;
    for (int i = beg; i < end; ++i) { off[i] = run; run += cnt[i]; }
    if (tid == 1023) off[n] = part[1023];
    __syncthreads();
  }
}

__global__ void k_fill(const int* __restrict__ src, const int* __restrict__ dst,
                       const int* __restrict__ offf, const int* __restrict__ offr,
                       int* __restrict__ curf, int* __restrict__ curr,
                       int* __restrict__ eidf, int* __restrict__ eidr, int E) {
  int e = blockIdx.x * 256 + threadIdx.x;
  if (e >= E) return;
  int d = dst[e];
  int p = atomicAdd(&curf[d], 1);
  eidf[offf[d] + p] = e;
  int s = src[e];
  p = atomicAdd(&curr[s], 1);
  eidr[offr[s] + p] = e;
}

// ---------------- K5: scores in sorted order ----------------
__global__ void k_scores(const int* __restrict__ src, const int* __restrict__ dst,
                         const int* __restrict__ eidf, const int* __restrict__ eidr,
                         const float* __restrict__ zs1, const float* __restrict__ zs2,
                         const float* __restrict__ zs3, const float* __restrict__ ze1,
                         const float* __restrict__ ze2, const float* __restrict__ ze3,
                         float* __restrict__ sf, float* __restrict__ sef,
                         float* __restrict__ sr, float* __restrict__ ser, int E) {
  int p = blockIdx.x * 256 + threadIdx.x;
  if (p >= E) return;
  {
    int e = eidf[p];
    int s = src[e], d = dst[e];
    float z2 = zs2[e], ze2v = ze2[e];
    sf[p] = lrelu(zs1[s] + z2 + zs3[d]);
    sef[p] = lrelu(ze1[s] + ze2v + ze3[d]);
  }
  {
    int e = eidr[p];
    int s = src[e], d = dst[e];
    float z2 = zs2[e], ze2v = ze2[e];
    sr[p] = lrelu(zs1[d] + z2 + zs3[s]);
    ser[p] = lrelu(ze1[d] + ze2v + ze3[s]);
  }
}

// ---------------- K6: softmax+aggregate (round-14 verbatim) ----------------
__device__ inline float wred_max64(float v) {
#pragma unroll
  for (int mk = 32; mk; mk >>= 1) v = fmaxf(v, __shfl_xor(v, mk));
  return v;
}
__device__ inline float wred_sum64(float v) {
#pragma unroll
  for (int mk = 32; mk; mk >>= 1) v += __shfl_xor(v, mk);
  return v;
}

__global__ __launch_bounds__(256) void k_agg4(const int* __restrict__ offf, const int* __restrict__ eidf,
                                              const int* __restrict__ offr, const int* __restrict__ eidr,
                                              const int* __restrict__ src, const int* __restrict__ dst,
                                              const float* __restrict__ sf, const float* __restrict__ sef,
                                              const float* __restrict__ sr, const float* __restrict__ ser,
                                              const unsigned short* __restrict__ hh,
                                              const unsigned short* __restrict__ ejh,
                                              float* __restrict__ agg2, int n) {
  int gw = blockIdx.x * 4 + (threadIdx.x >> 6);
  int lane = threadIdx.x & 63;
  if (gw >= 2 * n) return;
  int dir = gw & 1;
  int v = gw >> 1;
  const int* off = dir ? offr : offf;
  const int* eid = dir ? eidr : eidf;
  const float* sc  = dir ? sr  : sf;
  const float* sce = dir ? ser : sef;
  const int* nbr = dir ? dst : src;
  int s0 = off[v], s1 = off[v + 1];
  float m1 = -1e30f, m2 = -1e30f;
  for (int i = s0 + lane; i < s1; i += 64) {
    m1 = fmaxf(m1, sc[i]);
    m2 = fmaxf(m2, sce[i]);
  }
  m1 = wred_max64(m1); m2 = wred_max64(m2);
  float d1 = 0.f, d2 = 0.f;
  for (int i = s0 + lane; i < s1; i += 64) {
    d1 += __expf(sc[i] - m1);
    d2 += __expf(sce[i] - m2);
  }
  d1 = wred_sum64(d1); d2 = wred_sum64(d2);
  float i1 = (s1 > s0) ? 1.f / d1 : 0.f;
  float i2 = (s1 > s0) ? 1.f / d2 : 0.f;
  float aH0 = 0.f, aH1 = 0.f, aE0 = 0.f, aE1 = 0.f;
  for (int i = s0; i < s1; ++i) {
    int e_ = eid[i];
    int nb = nbr[e_];
    float w1 = __expf(sc[i] - m1) * i1;
    float w2 = __expf(sce[i] - m2) * i2;
    unsigned hp = *(const unsigned*)&hh[(long)nb * 128 + 2 * lane];
    unsigned ep = *(const unsigned*)&ejh[(long)e_ * 128 + 2 * lane];
    aH0 += w1 * bf2f((unsigned short)(hp & 0xFFFFu));
    aH1 += w1 * bf2f((unsigned short)(hp >> 16));
    aE0 += w2 * bf2f((unsigned short)(ep & 0xFFFFu));
    aE1 += w2 * bf2f((unsigned short)(ep >> 16));
  }
  float* dstp = agg2 + ((long)dir * n + v) * 256;
  dstp[2 * lane] = aH0;
  dstp[2 * lane + 1] = aH1;
  dstp[128 + 2 * lane] = aE0;
  dstp[128 + 2 * lane + 1] = aE1;
}

// ---------------- K7: mix GEMM (fp16 MFMA) + LayerNorm + relu + residual ----------------
__global__ __launch_bounds__(256) void k_mix_ln(const float* __restrict__ A,   // agg2 [2][M][256]
                                                const _Float16* __restrict__ McT, // [128][256] fp16
                                                const float* __restrict__ bias,   // bmix (x2)
                                                const float* __restrict__ h,
                                                const float* __restrict__ g,
                                                const float* __restrict__ bn,
                                                float* __restrict__ outp, int M) {
  __shared__ _Float16 Als[64][264];  // stride 528B = 132 dwords % 32 = 4 -> conflict-free
  int tid = threadIdx.x;
  int lane = tid & 63, w = tid >> 6;
  int kgrp = lane >> 4, sub = lane & 15;
  long mbase = (long)blockIdx.x * 64;
  const float* A2 = A + (long)M * 256;
#pragma unroll
  for (int it = 0; it < 16; ++it) {
    int idx = tid + it * 256;      // 0..4095
    int r = idx >> 6, c4 = (idx & 63) * 4;
    long m = mbase + r;
    f16x4 hv = (f16x4){0, 0, 0, 0};
    if (m < M) {
      float4 v1 = *(const float4*)&A[m * 256 + c4];
      float4 v2 = *(const float4*)&A2[m * 256 + c4];
      hv[0] = (_Float16)(v1.x + v2.x);
      hv[1] = (_Float16)(v1.y + v2.y);
      hv[2] = (_Float16)(v1.z + v2.z);
      hv[3] = (_Float16)(v1.w + v2.w);
    }
    *(f16x4*)&Als[r][c4] = hv;
  }
  __syncthreads();

  int arow = w * 16 + sub;
  f32x4 acc[8];
#pragma unroll
  for (int t = 0; t < 8; ++t) acc[t] = (f32x4){0.f, 0.f, 0.f, 0.f};
#pragma unroll
  for (int ks = 0; ks < 8; ++ks) {
    f16x8 a = *(const f16x8*)&Als[arow][ks * 32 + kgrp * 8];
#pragma unroll
    for (int t = 0; t < 8; ++t) {
      f16x8 b = *(const f16x8*)&McT[(t * 16 + sub) * 256 + ks * 32 + kgrp * 8];
      acc[t] = __builtin_amdgcn_mfma_f32_16x16x32_f16(a, b, acc[t], 0, 0, 0);
    }
  }

  float bb[8], gv[8], bv[8];
#pragma unroll
  for (int t = 0; t < 8; ++t) {
    int c = t * 16 + sub;
    bb[t] = 2.f * bias[c];
    gv[t] = g[c];
    bv[t] = bn[c];
  }

  // epilogue: lane owns rows w*16+kgrp*4+r, cols t*16+sub; row group = 16 sub-lanes
#pragma unroll
  for (int r = 0; r < 4; ++r) {
    int rl = w * 16 + kgrp * 4 + r;
    long m = mbase + rl;
    float x[8];
    float s = 0.f, q = 0.f;
#pragma unroll
    for (int t = 0; t < 8; ++t) {
      x[t] = acc[t][r] + bb[t];
      s += x[t];
      q += x[t] * x[t];
    }
#pragma unroll
    for (int mk = 1; mk < 16; mk <<= 1) {
      s += __shfl_xor(s, mk);
      q += __shfl_xor(q, mk);
    }
    float mu = s * (1.f / 128.f);
    float var = q * (1.f / 128.f) - mu * mu;
    float rstd = rsqrtf(var + 1e-5f);
    if (m < M) {
      const float* hp = h + m * 128;
#pragma unroll
      for (int t = 0; t < 8; ++t) {
        int c = t * 16 + sub;
        outp[m * 128 + c] = fmaxf((x[t] - mu) * rstd * gv[t] + bv[t], 0.f) + hp[c];
      }
    }
  }
}

extern "C" void kernel_launch(void* const* d_in, const int* in_sizes, int n_in,
                              void* d_out, int out_size, void* d_ws, size_t ws_size,
                              hipStream_t stream) {
  const float* h = (const float*)d_in[0];
  const float* e = (const float*)d_in[1];
  const int* src = (const int*)d_in[2];
  const int* dst = (const int*)d_in[3];
  const float* Wfc = (const float*)d_in[4];
  const float* Wfce = (const float*)d_in[5];
  const float* aat = (const float*)d_in[6];
  const float* aate = (const float*)d_in[7];
  const float* WB1 = (const float*)d_in[8];
  const float* bB1 = (const float*)d_in[9];
  const float* WB2 = (const float*)d_in[10];
  const float* bB2 = (const float*)d_in[11];
  const float* WB3 = (const float*)d_in[12];
  const float* bB3 = (const float*)d_in[13];
  const float* Wmix = (const float*)d_in[14];
  const float* bmix = (const float*)d_in[15];
  const float* lng = (const float*)d_in[16];
  const float* lnb = (const float*)d_in[17];
  int n = in_sizes[0] / 128;
  int E = in_sizes[1] / 128;

  float* hout = (float*)d_out;
  float* eout = (float*)d_out + (size_t)n * 128;

  char* w = (char*)d_ws;
  auto alloc = [&](size_t bytes) {
    void* p = w;
    w += (bytes + 255) / 256 * 256;
    return p;
  };
  float* B1h = (float*)alloc((size_t)n * 128 * 4);
  float* B2h = (float*)alloc((size_t)n * 128 * 4);
  float* agg2 = (float*)alloc((size_t)n * 512 * 4);
  float* zs1 = (float*)alloc((size_t)n * 4);
  float* zs3 = (float*)alloc((size_t)n * 4);
  float* ze1 = (float*)alloc((size_t)n * 4);
  float* ze3 = (float*)alloc((size_t)n * 4);
  float* zs2 = (float*)alloc((size_t)E * 4);
  float* ze2 = (float*)alloc((size_t)E * 4);
  float* sf = (float*)alloc((size_t)E * 4);
  float* sef = (float*)alloc((size_t)E * 4);
  float* sr = (float*)alloc((size_t)E * 4);
  float* ser = (float*)alloc((size_t)E * 4);
  float* Mc = (float*)alloc(256 * 128 * 4);
  float* cvec = (float*)alloc(768 * 4);
  _Float16* WT = (_Float16*)alloc(128 * 128 * 2);
  _Float16* W1T = (_Float16*)alloc(128 * 128 * 2);
  _Float16* W2T = (_Float16*)alloc(128 * 128 * 2);
  _Float16* McT = (_Float16*)alloc(128 * 256 * 2);
  int* offf = (int*)alloc((size_t)(n + 1) * 4);
  int* offr = (int*)alloc((size_t)(n + 1) * 4);
  size_t curpad = ((size_t)n * 4 + 255) / 256 * 256;
  int* curf = (int*)alloc((size_t)n * 4);
  int* curr = (int*)alloc((size_t)n * 4);
  int* eidf = (int*)alloc((size_t)E * 4);
  int* eidr = (int*)alloc((size_t)E * 4);
  unsigned short* ejh = (unsigned short*)alloc((size_t)E * 128 * 2);
  unsigned short* hh = (unsigned short*)alloc((size_t)n * 128 * 2);

  hipMemsetAsync(curf, 0, curpad * 2, stream);  // curf + curr (adjacent)

  k_combine<<<262, 128, 0, stream>>>(Wfc, Wfce, Wmix, aat, aate, Mc, cvec);
  k_wt3<<<192, 256, 0, stream>>>(WB3, WB1, WB2, WT, W1T, W2T);
  k_mcT<<<128, 256, 0, stream>>>(Mc, McT);
  k_gemm_dual<<<(n + 63) / 64, 256, 0, stream>>>(h, W1T, bB1, W2T, bB2, cvec, B1h, B2h, hh,
                                                 zs1, zs3, ze1, ze3, n);
  k_hist<<<(E + 255) / 256, 256, 0, stream>>>(src, dst, curf, curr, E);
  k_scan<<<1, 1024, 0, stream>>>(curf, curr, offf, offr, n);
  hipMemsetAsync(curf, 0, curpad * 2, stream);
  k_fill<<<(E + 255) / 256, 256, 0, stream>>>(src, dst, offf, offr, curf, curr, eidf, eidr, E);
  k_edge<<<(E + 63) / 64, 256, 0, stream>>>(e, WT, bB3, B1h, B2h, src, dst,
                                            cvec + 128, cvec + 512, eout, ejh, zs2, ze2, E);
  k_scores<<<(E + 255) / 256, 256, 0, stream>>>(src, dst, eidf, eidr, zs1, zs2, zs3, ze1, ze2, ze3,
                                                sf, sef, sr, ser, E);
  k_agg4<<<(2 * n + 3) / 4, 256, 0, stream>>>(offf, eidf, offr, eidr, src, dst, sf, sef, sr, ser,
                                              hh, ejh, agg2, n);
  k_mix_ln<<<(n + 63) / 64, 256, 0, stream>>>(agg2, McT, bmix, h, lng, lnb, hout, n);
}

// Round 18
// 1121.592 us; speedup vs baseline: 1.1160x; 1.1160x over previous
//
#include <hip/hip_runtime.h>
#include <hip/hip_bf16.h>

// SymGAT fused layer. Round 18:
//  - B1h/B2h stored bf16 (B1hh/B2hh): gather working set 51->25.6MB (fits
//    aggregate L2); k_gemm_dual writes halved; k_edge gather bytes halved.
//  - k_agg4 weight loop manually unrolled x2 (doubles loads in flight on the
//    serial per-edge latency chain).
//  - everything else identical to round-17 baseline (fp16 LDS k_edge,
//    MFMA dual/mix_ln, hardware-verified MFMA mapping).

typedef _Float16 f16x8 __attribute__((ext_vector_type(8)));
typedef _Float16 f16x4 __attribute__((ext_vector_type(4)));
typedef float f32x4 __attribute__((ext_vector_type(4)));

__device__ inline float lrelu(float x) { return x > 0.f ? x : 0.01f * x; }

__device__ inline unsigned short f2bf(float f) {  // RNE float->bf16
  unsigned u = __float_as_uint(f);
  unsigned r = (u + 0x7FFFu + ((u >> 16) & 1u)) >> 16;
  return (unsigned short)r;
}
__device__ inline float bf2f(unsigned short us) {
  return __uint_as_float(((unsigned)us) << 16);
}

// ---------------- K0: weight combos ----------------
__global__ void k_combine(const float* __restrict__ Wfc, const float* __restrict__ Wfce,
                          const float* __restrict__ Wmix, const float* __restrict__ aat,
                          const float* __restrict__ aate, float* __restrict__ Mc,
                          float* __restrict__ cvec) {
  int b = blockIdx.x, j = threadIdx.x;
  if (b < 256) {
    const float* Arow;
    const float* Wm;
    if (b < 128) { Arow = Wfc + b * 128; Wm = Wmix; }
    else         { Arow = Wfce + (b - 128) * 128; Wm = Wmix + 128 * 128; }
    float acc = 0.f;
    for (int t = 0; t < 128; ++t) acc += Arow[t] * Wm[t * 128 + j];
    Mc[b * 128 + j] = acc;
  } else {
    int idx = b - 256;
    const float* W; const float* a;
    switch (idx) {
      case 0: W = Wfc;  a = aat;        break;  // c_s1 @ cvec+0
      case 1: W = Wfce; a = aat + 128;  break;  // c_s2 @ cvec+128
      case 2: W = Wfc;  a = aat + 256;  break;  // c_s3 @ cvec+256
      case 3: W = Wfc;  a = aate;       break;  // c_e1 @ cvec+384
      case 4: W = Wfce; a = aate + 128; break;  // c_e2 @ cvec+512
      default: W = Wfc; a = aate + 256; break;  // c_e3 @ cvec+640
    }
    float acc = 0.f;
    for (int t = 0; t < 128; ++t) acc += W[j * 128 + t] * a[t];
    cvec[idx * 128 + j] = acc;
  }
}

// ---------------- WT3: {W_B3, W_B1, W_B2} -> fp16 transposed ----------------
__global__ __launch_bounds__(256) void k_wt3(const float* __restrict__ W3,
                                             const float* __restrict__ W1,
                                             const float* __restrict__ W2,
                                             _Float16* __restrict__ WT,
                                             _Float16* __restrict__ W1T,
                                             _Float16* __restrict__ W2T) {
  int idx = blockIdx.x * 256 + threadIdx.x;  // 49152 total
  int which = idx >> 14;
  int r = idx & 16383;
  int c = r >> 7, k = r & 127;
  const float* s = (which == 0) ? W3 : (which == 1) ? W1 : W2;
  _Float16* d = (which == 0) ? WT : (which == 1) ? W1T : W2T;
  d[r] = (_Float16)s[k * 128 + c];
}

// ---------------- McT: Mc[256][128] -> fp16 transposed [128][256] ----------------
__global__ __launch_bounds__(256) void k_mcT(const float* __restrict__ Mc,
                                             _Float16* __restrict__ McT) {
  int idx = blockIdx.x * 256 + threadIdx.x;  // 32768 total
  int c = idx >> 8, k = idx & 255;
  McT[idx] = (_Float16)Mc[k * 128 + c];
}

// ---------------- K1: dual GEMM (fp16 MFMA) + nodevec dots + hh shadow ----------------
__global__ __launch_bounds__(256) void k_gemm_dual(const float* __restrict__ A,
                                                   const _Float16* __restrict__ W1T,
                                                   const float* __restrict__ b1v,
                                                   const _Float16* __restrict__ W2T,
                                                   const float* __restrict__ b2v,
                                                   const float* __restrict__ cvec,
                                                   unsigned short* __restrict__ B1hh,
                                                   unsigned short* __restrict__ B2hh,
                                                   unsigned short* __restrict__ hh,
                                                   float* __restrict__ zs1, float* __restrict__ zs3,
                                                   float* __restrict__ ze1, float* __restrict__ ze3,
                                                   int M) {
  __shared__ float Als[64][132];
  int tid = threadIdx.x;
  int lane = tid & 63, w = tid >> 6;
  int kgrp = lane >> 4, sub = lane & 15;
  long mbase = (long)blockIdx.x * 64;
#pragma unroll
  for (int it = 0; it < 8; ++it) {
    int idx = tid + it * 256;
    int r = idx >> 5, cv = idx & 31;
    long m = mbase + r;
    float4 v = make_float4(0.f, 0.f, 0.f, 0.f);
    if (m < M) v = *(const float4*)&A[m * 128 + 4 * cv];
    *(float4*)&Als[r][4 * cv] = v;
  }
  __syncthreads();

  int arow = w * 16 + sub;
  f16x8 afr[4];
#pragma unroll
  for (int ks = 0; ks < 4; ++ks) {
    float4 u0 = *(const float4*)&Als[arow][ks * 32 + kgrp * 8];
    float4 u1 = *(const float4*)&Als[arow][ks * 32 + kgrp * 8 + 4];
    f16x8 a;
    a[0] = (_Float16)u0.x; a[1] = (_Float16)u0.y; a[2] = (_Float16)u0.z; a[3] = (_Float16)u0.w;
    a[4] = (_Float16)u1.x; a[5] = (_Float16)u1.y; a[6] = (_Float16)u1.z; a[7] = (_Float16)u1.w;
    afr[ks] = a;
  }

  f32x4 acc1[8], acc2[8];
#pragma unroll
  for (int t = 0; t < 8; ++t) {
    acc1[t] = (f32x4){0.f, 0.f, 0.f, 0.f};
    acc2[t] = (f32x4){0.f, 0.f, 0.f, 0.f};
  }
#pragma unroll
  for (int ks = 0; ks < 4; ++ks)
#pragma unroll
    for (int t = 0; t < 8; ++t) {
      int boff = (t * 16 + sub) * 128 + ks * 32 + kgrp * 8;
      f16x8 b1 = *(const f16x8*)&W1T[boff];
      acc1[t] = __builtin_amdgcn_mfma_f32_16x16x32_f16(afr[ks], b1, acc1[t], 0, 0, 0);
      f16x8 b2 = *(const f16x8*)&W2T[boff];
      acc2[t] = __builtin_amdgcn_mfma_f32_16x16x32_f16(afr[ks], b2, acc2[t], 0, 0, 0);
    }

  float bb1[8], bb2[8];
#pragma unroll
  for (int t = 0; t < 8; ++t) {
    int c = t * 16 + sub;
    bb1[t] = b1v[c];
    bb2[t] = b2v[c];
  }

  // epilogue in MFMA lane layout; z-dots and hh from EXACT fp32 h in Als
#pragma unroll
  for (int r = 0; r < 4; ++r) {
    int rl = w * 16 + kgrp * 4 + r;
    long m = mbase + rl;
    float p1 = 0.f, p3 = 0.f, q1 = 0.f, q3 = 0.f;
    if (m < M) {
#pragma unroll
      for (int t = 0; t < 8; ++t) {
        int c = t * 16 + sub;
        float a = Als[rl][c];
        B1hh[m * 128 + c] = f2bf(acc1[t][r] + bb1[t]);
        B2hh[m * 128 + c] = f2bf(acc2[t][r] + bb2[t]);
        hh[m * 128 + c] = f2bf(a);
        p1 += a * cvec[c];
        p3 += a * cvec[256 + c];
        q1 += a * cvec[384 + c];
        q3 += a * cvec[640 + c];
      }
    }
#pragma unroll
    for (int mk = 1; mk < 16; mk <<= 1) {
      p1 += __shfl_xor(p1, mk); p3 += __shfl_xor(p3, mk);
      q1 += __shfl_xor(q1, mk); q3 += __shfl_xor(q3, mk);
    }
    if (m < M && sub == 0) { zs1[m] = p1; zs3[m] = p3; ze1[m] = q1; ze3[m] = q3; }
  }
}

// ---------------- K2: fused edge kernel (fp16 MFMA, fp16 LDS, bf16 gathers) ----------------
__global__ __launch_bounds__(256) void k_edge(const float* __restrict__ e,
                                              const _Float16* __restrict__ WT,
                                              const float* __restrict__ bias,
                                              const unsigned short* __restrict__ B1hh,
                                              const unsigned short* __restrict__ B2hh,
                                              const int* __restrict__ src, const int* __restrict__ dst,
                                              const float* __restrict__ cs2, const float* __restrict__ ce2,
                                              float* __restrict__ eout, unsigned short* __restrict__ ejh,
                                              float* __restrict__ zs2, float* __restrict__ ze2, int M) {
  __shared__ _Float16 Els[64][136];  // 17.4KB; row stride 272B = 68 dwords % 32 = 4
  int tid = threadIdx.x;
  int lane = tid & 63, w = tid >> 6;
  int kgrp = lane >> 4, sub = lane & 15;
  long mbase = (long)blockIdx.x * 64;
#pragma unroll
  for (int it = 0; it < 8; ++it) {
    int idx = tid + it * 256;
    int r = idx >> 5, cv = idx & 31;
    long m = mbase + r;
    float4 v = make_float4(0.f, 0.f, 0.f, 0.f);
    if (m < M) v = *(const float4*)&e[m * 128 + 4 * cv];
    f16x4 hv;
    hv[0] = (_Float16)v.x; hv[1] = (_Float16)v.y;
    hv[2] = (_Float16)v.z; hv[3] = (_Float16)v.w;
    *(f16x4*)&Els[r][4 * cv] = hv;
  }
  __syncthreads();

  int arow = w * 16 + sub;
  f16x8 afr[4];
#pragma unroll
  for (int ks = 0; ks < 4; ++ks)
    afr[ks] = *(const f16x8*)&Els[arow][ks * 32 + kgrp * 8];

  f32x4 acc[8];
#pragma unroll
  for (int t = 0; t < 8; ++t) acc[t] = (f32x4){0.f, 0.f, 0.f, 0.f};
#pragma unroll
  for (int ks = 0; ks < 4; ++ks)
#pragma unroll
    for (int t = 0; t < 8; ++t) {
      f16x8 b = *(const f16x8*)&WT[(t * 16 + sub) * 128 + ks * 32 + kgrp * 8];
      acc[t] = __builtin_amdgcn_mfma_f32_16x16x32_f16(afr[ks], b, acc[t], 0, 0, 0);
    }

  float bb[8], cs[8], ce[8];
#pragma unroll
  for (int t = 0; t < 8; ++t) {
    int c = t * 16 + sub;
    bb[t] = bias[c];
    cs[t] = cs2[c];
    ce[t] = ce2[c];
  }

  // epilogue in MFMA lane layout: lane owns rows w*16+kgrp*4+r, cols t*16+sub
#pragma unroll
  for (int r = 0; r < 4; ++r) {
    int rl = w * 16 + kgrp * 4 + r;
    long m = mbase + rl;
    float ps = 0.f, pe = 0.f;
    if (m < M) {
      int s = src[m], dv = dst[m];
      const unsigned short* b1p = B1hh + (long)s * 128;
      const unsigned short* b2p = B2hh + (long)dv * 128;
#pragma unroll
      for (int t = 0; t < 8; ++t) {
        int c = t * 16 + sub;
        float o = fmaxf(acc[t][r] + bb[t] + bf2f(b1p[c]) + bf2f(b2p[c]), 0.f) + (float)Els[rl][c];
        eout[m * 128 + c] = o;
        ejh[m * 128 + c] = f2bf(o);
        ps += o * cs[t];
        pe += o * ce[t];
      }
    }
#pragma unroll
    for (int mk = 1; mk < 16; mk <<= 1) {
      ps += __shfl_xor(ps, mk);
      pe += __shfl_xor(pe, mk);
    }
    if (m < M && sub == 0) { zs2[m] = ps; ze2[m] = pe; }
  }
}

// ---------------- CSR build ----------------
__global__ void k_hist(const int* __restrict__ src, const int* __restrict__ dst,
                       int* __restrict__ cntf, int* __restrict__ cntr, int E) {
  int e = blockIdx.x * 256 + threadIdx.x;
  if (e < E) {
    atomicAdd(&cntf[dst[e]], 1);
    atomicAdd(&cntr[src[e]], 1);
  }
}

__global__ __launch_bounds__(1024) void k_scan(const int* __restrict__ cntf,
                                               const int* __restrict__ cntr,
                                               int* __restrict__ offf, int* __restrict__ offr, int n) {
  __shared__ int part[1024];
  int tid = threadIdx.x;
  for (int pass = 0; pass < 2; ++pass) {
    const int* cnt = pass ? cntr : cntf;
    int* off = pass ? offr : offf;
    int per = (n + 1023) >> 10;
    int beg = tid * per; if (beg > n) beg = n;
    int end = beg + per; if (end > n) end = n;
    int s = 0;
    for (int i = beg; i < end; ++i) s += cnt[i];
    part[tid] = s;
    __syncthreads();
    for (int o = 1; o < 1024; o <<= 1) {
      int vv = (tid >= o) ? part[tid - o] : 0;
      __syncthreads();
      part[tid] += vv;
      __syncthreads();
    }
    int run = tid ? part[tid - 1] : 0;
    for (int i = beg; i < end; ++i) { off[i] = run; run += cnt[i]; }
    if (tid == 1023) off[n] = part[1023];
    __syncthreads();
  }
}

__global__ void k_fill(const int* __restrict__ src, const int* __restrict__ dst,
                       const int* __restrict__ offf, const int* __restrict__ offr,
                       int* __restrict__ curf, int* __restrict__ curr,
                       int* __restrict__ eidf, int* __restrict__ eidr, int E) {
  int e = blockIdx.x * 256 + threadIdx.x;
  if (e >= E) return;
  int d = dst[e];
  int p = atomicAdd(&curf[d], 1);
  eidf[offf[d] + p] = e;
  int s = src[e];
  p = atomicAdd(&curr[s], 1);
  eidr[offr[s] + p] = e;
}

// ---------------- K5: scores in sorted order ----------------
__global__ void k_scores(const int* __restrict__ src, const int* __restrict__ dst,
                         const int* __restrict__ eidf, const int* __restrict__ eidr,
                         const float* __restrict__ zs1, const float* __restrict__ zs2,
                         const float* __restrict__ zs3, const float* __restrict__ ze1,
                         const float* __restrict__ ze2, const float* __restrict__ ze3,
                         float* __restrict__ sf, float* __restrict__ sef,
                         float* __restrict__ sr, float* __restrict__ ser, int E) {
  int p = blockIdx.x * 256 + threadIdx.x;
  if (p >= E) return;
  {
    int e = eidf[p];
    int s = src[e], d = dst[e];
    float z2 = zs2[e], ze2v = ze2[e];
    sf[p] = lrelu(zs1[s] + z2 + zs3[d]);
    sef[p] = lrelu(ze1[s] + ze2v + ze3[d]);
  }
  {
    int e = eidr[p];
    int s = src[e], d = dst[e];
    float z2 = zs2[e], ze2v = ze2[e];
    sr[p] = lrelu(zs1[d] + z2 + zs3[s]);
    ser[p] = lrelu(ze1[d] + ze2v + ze3[s]);
  }
}

// ---------------- K6: softmax+aggregate (weight loop 2x unrolled) ----------------
__device__ inline float wred_max64(float v) {
#pragma unroll
  for (int mk = 32; mk; mk >>= 1) v = fmaxf(v, __shfl_xor(v, mk));
  return v;
}
__device__ inline float wred_sum64(float v) {
#pragma unroll
  for (int mk = 32; mk; mk >>= 1) v += __shfl_xor(v, mk);
  return v;
}

__global__ __launch_bounds__(256) void k_agg4(const int* __restrict__ offf, const int* __restrict__ eidf,
                                              const int* __restrict__ offr, const int* __restrict__ eidr,
                                              const int* __restrict__ src, const int* __restrict__ dst,
                                              const float* __restrict__ sf, const float* __restrict__ sef,
                                              const float* __restrict__ sr, const float* __restrict__ ser,
                                              const unsigned short* __restrict__ hh,
                                              const unsigned short* __restrict__ ejh,
                                              float* __restrict__ agg2, int n) {
  int gw = blockIdx.x * 4 + (threadIdx.x >> 6);
  int lane = threadIdx.x & 63;
  if (gw >= 2 * n) return;
  int dir = gw & 1;
  int v = gw >> 1;
  const int* off = dir ? offr : offf;
  const int* eid = dir ? eidr : eidf;
  const float* sc  = dir ? sr  : sf;
  const float* sce = dir ? ser : sef;
  const int* nbr = dir ? dst : src;
  int s0 = off[v], s1 = off[v + 1];
  float m1 = -1e30f, m2 = -1e30f;
  for (int i = s0 + lane; i < s1; i += 64) {
    m1 = fmaxf(m1, sc[i]);
    m2 = fmaxf(m2, sce[i]);
  }
  m1 = wred_max64(m1); m2 = wred_max64(m2);
  float d1 = 0.f, d2 = 0.f;
  for (int i = s0 + lane; i < s1; i += 64) {
    d1 += __expf(sc[i] - m1);
    d2 += __expf(sce[i] - m2);
  }
  d1 = wred_sum64(d1); d2 = wred_sum64(d2);
  float i1 = (s1 > s0) ? 1.f / d1 : 0.f;
  float i2 = (s1 > s0) ? 1.f / d2 : 0.f;
  float aH0 = 0.f, aH1 = 0.f, aE0 = 0.f, aE1 = 0.f;
  int i = s0;
  for (; i + 1 < s1; i += 2) {
    int eA = eid[i], eB = eid[i + 1];
    int nA = nbr[eA], nB = nbr[eB];
    unsigned hpA = *(const unsigned*)&hh[(long)nA * 128 + 2 * lane];
    unsigned epA = *(const unsigned*)&ejh[(long)eA * 128 + 2 * lane];
    unsigned hpB = *(const unsigned*)&hh[(long)nB * 128 + 2 * lane];
    unsigned epB = *(const unsigned*)&ejh[(long)eB * 128 + 2 * lane];
    float w1A = __expf(sc[i] - m1) * i1;
    float w2A = __expf(sce[i] - m2) * i2;
    float w1B = __expf(sc[i + 1] - m1) * i1;
    float w2B = __expf(sce[i + 1] - m2) * i2;
    aH0 += w1A * bf2f((unsigned short)(hpA & 0xFFFFu)) + w1B * bf2f((unsigned short)(hpB & 0xFFFFu));
    aH1 += w1A * bf2f((unsigned short)(hpA >> 16)) + w1B * bf2f((unsigned short)(hpB >> 16));
    aE0 += w2A * bf2f((unsigned short)(epA & 0xFFFFu)) + w2B * bf2f((unsigned short)(epB & 0xFFFFu));
    aE1 += w2A * bf2f((unsigned short)(epA >> 16)) + w2B * bf2f((unsigned short)(epB >> 16));
  }
  if (i < s1) {
    int e_ = eid[i];
    int nb = nbr[e_];
    float w1 = __expf(sc[i] - m1) * i1;
    float w2 = __expf(sce[i] - m2) * i2;
    unsigned hp = *(const unsigned*)&hh[(long)nb * 128 + 2 * lane];
    unsigned ep = *(const unsigned*)&ejh[(long)e_ * 128 + 2 * lane];
    aH0 += w1 * bf2f((unsigned short)(hp & 0xFFFFu));
    aH1 += w1 * bf2f((unsigned short)(hp >> 16));
    aE0 += w2 * bf2f((unsigned short)(ep & 0xFFFFu));
    aE1 += w2 * bf2f((unsigned short)(ep >> 16));
  }
  float* dstp = agg2 + ((long)dir * n + v) * 256;
  dstp[2 * lane] = aH0;
  dstp[2 * lane + 1] = aH1;
  dstp[128 + 2 * lane] = aE0;
  dstp[128 + 2 * lane + 1] = aE1;
}

// ---------------- K7: mix GEMM (fp16 MFMA) + LayerNorm + relu + residual ----------------
__global__ __launch_bounds__(256) void k_mix_ln(const float* __restrict__ A,   // agg2 [2][M][256]
                                                const _Float16* __restrict__ McT, // [128][256] fp16
                                                const float* __restrict__ bias,   // bmix (x2)
                                                const float* __restrict__ h,
                                                const float* __restrict__ g,
                                                const float* __restrict__ bn,
                                                float* __restrict__ outp, int M) {
  __shared__ _Float16 Als[64][264];  // stride 528B = 132 dwords % 32 = 4 -> conflict-free
  int tid = threadIdx.x;
  int lane = tid & 63, w = tid >> 6;
  int kgrp = lane >> 4, sub = lane & 15;
  long mbase = (long)blockIdx.x * 64;
  const float* A2 = A + (long)M * 256;
#pragma unroll
  for (int it = 0; it < 16; ++it) {
    int idx = tid + it * 256;      // 0..4095
    int r = idx >> 6, c4 = (idx & 63) * 4;
    long m = mbase + r;
    f16x4 hv = (f16x4){0, 0, 0, 0};
    if (m < M) {
      float4 v1 = *(const float4*)&A[m * 256 + c4];
      float4 v2 = *(const float4*)&A2[m * 256 + c4];
      hv[0] = (_Float16)(v1.x + v2.x);
      hv[1] = (_Float16)(v1.y + v2.y);
      hv[2] = (_Float16)(v1.z + v2.z);
      hv[3] = (_Float16)(v1.w + v2.w);
    }
    *(f16x4*)&Als[r][c4] = hv;
  }
  __syncthreads();

  int arow = w * 16 + sub;
  f32x4 acc[8];
#pragma unroll
  for (int t = 0; t < 8; ++t) acc[t] = (f32x4){0.f, 0.f, 0.f, 0.f};
#pragma unroll
  for (int ks = 0; ks < 8; ++ks) {
    f16x8 a = *(const f16x8*)&Als[arow][ks * 32 + kgrp * 8];
#pragma unroll
    for (int t = 0; t < 8; ++t) {
      f16x8 b = *(const f16x8*)&McT[(t * 16 + sub) * 256 + ks * 32 + kgrp * 8];
      acc[t] = __builtin_amdgcn_mfma_f32_16x16x32_f16(a, b, acc[t], 0, 0, 0);
    }
  }

  float bb[8], gv[8], bv[8];
#pragma unroll
  for (int t = 0; t < 8; ++t) {
    int c = t * 16 + sub;
    bb[t] = 2.f * bias[c];
    gv[t] = g[c];
    bv[t] = bn[c];
  }

  // epilogue: lane owns rows w*16+kgrp*4+r, cols t*16+sub; row group = 16 sub-lanes
#pragma unroll
  for (int r = 0; r < 4; ++r) {
    int rl = w * 16 + kgrp * 4 + r;
    long m = mbase + rl;
    float x[8];
    float s = 0.f, q = 0.f;
#pragma unroll
    for (int t = 0; t < 8; ++t) {
      x[t] = acc[t][r] + bb[t];
      s += x[t];
      q += x[t] * x[t];
    }
#pragma unroll
    for (int mk = 1; mk < 16; mk <<= 1) {
      s += __shfl_xor(s, mk);
      q += __shfl_xor(q, mk);
    }
    float mu = s * (1.f / 128.f);
    float var = q * (1.f / 128.f) - mu * mu;
    float rstd = rsqrtf(var + 1e-5f);
    if (m < M) {
      const float* hp = h + m * 128;
#pragma unroll
      for (int t = 0; t < 8; ++t) {
        int c = t * 16 + sub;
        outp[m * 128 + c] = fmaxf((x[t] - mu) * rstd * gv[t] + bv[t], 0.f) + hp[c];
      }
    }
  }
}

extern "C" void kernel_launch(void* const* d_in, const int* in_sizes, int n_in,
                              void* d_out, int out_size, void* d_ws, size_t ws_size,
                              hipStream_t stream) {
  const float* h = (const float*)d_in[0];
  const float* e = (const float*)d_in[1];
  const int* src = (const int*)d_in[2];
  const int* dst = (const int*)d_in[3];
  const float* Wfc = (const float*)d_in[4];
  const float* Wfce = (const float*)d_in[5];
  const float* aat = (const float*)d_in[6];
  const float* aate = (const float*)d_in[7];
  const float* WB1 = (const float*)d_in[8];
  const float* bB1 = (const float*)d_in[9];
  const float* WB2 = (const float*)d_in[10];
  const float* bB2 = (const float*)d_in[11];
  const float* WB3 = (const float*)d_in[12];
  const float* bB3 = (const float*)d_in[13];
  const float* Wmix = (const float*)d_in[14];
  const float* bmix = (const float*)d_in[15];
  const float* lng = (const float*)d_in[16];
  const float* lnb = (const float*)d_in[17];
  int n = in_sizes[0] / 128;
  int E = in_sizes[1] / 128;

  float* hout = (float*)d_out;
  float* eout = (float*)d_out + (size_t)n * 128;

  char* w = (char*)d_ws;
  auto alloc = [&](size_t bytes) {
    void* p = w;
    w += (bytes + 255) / 256 * 256;
    return p;
  };
  unsigned short* B1hh = (unsigned short*)alloc((size_t)n * 128 * 2);
  unsigned short* B2hh = (unsigned short*)alloc((size_t)n * 128 * 2);
  float* agg2 = (float*)alloc((size_t)n * 512 * 4);
  float* zs1 = (float*)alloc((size_t)n * 4);
  float* zs3 = (float*)alloc((size_t)n * 4);
  float* ze1 = (float*)alloc((size_t)n * 4);
  float* ze3 = (float*)alloc((size_t)n * 4);
  float* zs2 = (float*)alloc((size_t)E * 4);
  float* ze2 = (float*)alloc((size_t)E * 4);
  float* sf = (float*)alloc((size_t)E * 4);
  float* sef = (float*)alloc((size_t)E * 4);
  float* sr = (float*)alloc((size_t)E * 4);
  float* ser = (float*)alloc((size_t)E * 4);
  float* Mc = (float*)alloc(256 * 128 * 4);
  float* cvec = (float*)alloc(768 * 4);
  _Float16* WT = (_Float16*)alloc(128 * 128 * 2);
  _Float16* W1T = (_Float16*)alloc(128 * 128 * 2);
  _Float16* W2T = (_Float16*)alloc(128 * 128 * 2);
  _Float16* McT = (_Float16*)alloc(128 * 256 * 2);
  int* offf = (int*)alloc((size_t)(n + 1) * 4);
  int* offr = (int*)alloc((size_t)(n + 1) * 4);
  size_t curpad = ((size_t)n * 4 + 255) / 256 * 256;
  int* curf = (int*)alloc((size_t)n * 4);
  int* curr = (int*)alloc((size_t)n * 4);
  int* eidf = (int*)alloc((size_t)E * 4);
  int* eidr = (int*)alloc((size_t)E * 4);
  unsigned short* ejh = (unsigned short*)alloc((size_t)E * 128 * 2);
  unsigned short* hh = (unsigned short*)alloc((size_t)n * 128 * 2);

  hipMemsetAsync(curf, 0, curpad * 2, stream);  // curf + curr (adjacent)

  k_combine<<<262, 128, 0, stream>>>(Wfc, Wfce, Wmix, aat, aate, Mc, cvec);
  k_wt3<<<192, 256, 0, stream>>>(WB3, WB1, WB2, WT, W1T, W2T);
  k_mcT<<<128, 256, 0, stream>>>(Mc, McT);
  k_gemm_dual<<<(n + 63) / 64, 256, 0, stream>>>(h, W1T, bB1, W2T, bB2, cvec, B1hh, B2hh, hh,
                                                 zs1, zs3, ze1, ze3, n);
  k_hist<<<(E + 255) / 256, 256, 0, stream>>>(src, dst, curf, curr, E);
  k_scan<<<1, 1024, 0, stream>>>(curf, curr, offf, offr, n);
  hipMemsetAsync(curf, 0, curpad * 2, stream);
  k_fill<<<(E + 255) / 256, 256, 0, stream>>>(src, dst, offf, offr, curf, curr, eidf, eidr, E);
  k_edge<<<(E + 63) / 64, 256, 0, stream>>>(e, WT, bB3, B1hh, B2hh, src, dst,
                                            cvec + 128, cvec + 512, eout, ejh, zs2, ze2, E);
  k_scores<<<(E + 255) / 256, 256, 0, stream>>>(src, dst, eidf, eidr, zs1, zs2, zs3, ze1, ze2, ze3,
                                                sf, sef, sr, ser, E);
  k_agg4<<<(2 * n + 3) / 4, 256, 0, stream>>>(offf, eidf, offr, eidr, src, dst, sf, sef, sr, ser,
                                              hh, ejh, agg2, n);
  k_mix_ln<<<(n + 63) / 64, 256, 0, stream>>>(agg2, McT, bmix, h, lng, lnb, hout, n);
}

// Round 19
// 1079.689 us; speedup vs baseline: 1.1593x; 1.0388x over previous
//
#include <hip/hip_runtime.h>
#include <hip/hip_bf16.h>

// SymGAT fused layer. Round 19: round-18 baseline (1122us) plus
//  - agg2 stored fp16 (k_mix_ln converts to fp16 anyway): ~100MB less traffic.
//  - k_agg4 weight loop 4x unrolled (8 row-gathers in flight).
//  - McT written fp16-transposed directly by k_combine (k_mcT + Mc dropped).

typedef _Float16 f16x8 __attribute__((ext_vector_type(8)));
typedef _Float16 f16x4 __attribute__((ext_vector_type(4)));
typedef _Float16 f16x2 __attribute__((ext_vector_type(2)));
typedef float f32x4 __attribute__((ext_vector_type(4)));

__device__ inline float lrelu(float x) { return x > 0.f ? x : 0.01f * x; }

__device__ inline unsigned short f2bf(float f) {  // RNE float->bf16
  unsigned u = __float_as_uint(f);
  unsigned r = (u + 0x7FFFu + ((u >> 16) & 1u)) >> 16;
  return (unsigned short)r;
}
__device__ inline float bf2f(unsigned short us) {
  return __uint_as_float(((unsigned)us) << 16);
}

// ---------------- K0: weight combos (McT written fp16 transposed) ----------------
__global__ void k_combine(const float* __restrict__ Wfc, const float* __restrict__ Wfce,
                          const float* __restrict__ Wmix, const float* __restrict__ aat,
                          const float* __restrict__ aate, _Float16* __restrict__ McT,
                          float* __restrict__ cvec) {
  int b = blockIdx.x, j = threadIdx.x;
  if (b < 256) {
    const float* Arow;
    const float* Wm;
    if (b < 128) { Arow = Wfc + b * 128; Wm = Wmix; }
    else         { Arow = Wfce + (b - 128) * 128; Wm = Wmix + 128 * 128; }
    float acc = 0.f;
    for (int t = 0; t < 128; ++t) acc += Arow[t] * Wm[t * 128 + j];
    McT[j * 256 + b] = (_Float16)acc;   // transposed fp16
  } else {
    int idx = b - 256;
    const float* W; const float* a;
    switch (idx) {
      case 0: W = Wfc;  a = aat;        break;  // c_s1 @ cvec+0
      case 1: W = Wfce; a = aat + 128;  break;  // c_s2 @ cvec+128
      case 2: W = Wfc;  a = aat + 256;  break;  // c_s3 @ cvec+256
      case 3: W = Wfc;  a = aate;       break;  // c_e1 @ cvec+384
      case 4: W = Wfce; a = aate + 128; break;  // c_e2 @ cvec+512
      default: W = Wfc; a = aate + 256; break;  // c_e3 @ cvec+640
    }
    float acc = 0.f;
    for (int t = 0; t < 128; ++t) acc += W[j * 128 + t] * a[t];
    cvec[idx * 128 + j] = acc;
  }
}

// ---------------- WT3: {W_B3, W_B1, W_B2} -> fp16 transposed ----------------
__global__ __launch_bounds__(256) void k_wt3(const float* __restrict__ W3,
                                             const float* __restrict__ W1,
                                             const float* __restrict__ W2,
                                             _Float16* __restrict__ WT,
                                             _Float16* __restrict__ W1T,
                                             _Float16* __restrict__ W2T) {
  int idx = blockIdx.x * 256 + threadIdx.x;  // 49152 total
  int which = idx >> 14;
  int r = idx & 16383;
  int c = r >> 7, k = r & 127;
  const float* s = (which == 0) ? W3 : (which == 1) ? W1 : W2;
  _Float16* d = (which == 0) ? WT : (which == 1) ? W1T : W2T;
  d[r] = (_Float16)s[k * 128 + c];
}

// ---------------- K1: dual GEMM (fp16 MFMA) + nodevec dots + hh shadow ----------------
__global__ __launch_bounds__(256) void k_gemm_dual(const float* __restrict__ A,
                                                   const _Float16* __restrict__ W1T,
                                                   const float* __restrict__ b1v,
                                                   const _Float16* __restrict__ W2T,
                                                   const float* __restrict__ b2v,
                                                   const float* __restrict__ cvec,
                                                   unsigned short* __restrict__ B1hh,
                                                   unsigned short* __restrict__ B2hh,
                                                   unsigned short* __restrict__ hh,
                                                   float* __restrict__ zs1, float* __restrict__ zs3,
                                                   float* __restrict__ ze1, float* __restrict__ ze3,
                                                   int M) {
  __shared__ float Als[64][132];
  int tid = threadIdx.x;
  int lane = tid & 63, w = tid >> 6;
  int kgrp = lane >> 4, sub = lane & 15;
  long mbase = (long)blockIdx.x * 64;
#pragma unroll
  for (int it = 0; it < 8; ++it) {
    int idx = tid + it * 256;
    int r = idx >> 5, cv = idx & 31;
    long m = mbase + r;
    float4 v = make_float4(0.f, 0.f, 0.f, 0.f);
    if (m < M) v = *(const float4*)&A[m * 128 + 4 * cv];
    *(float4*)&Als[r][4 * cv] = v;
  }
  __syncthreads();

  int arow = w * 16 + sub;
  f16x8 afr[4];
#pragma unroll
  for (int ks = 0; ks < 4; ++ks) {
    float4 u0 = *(const float4*)&Als[arow][ks * 32 + kgrp * 8];
    float4 u1 = *(const float4*)&Als[arow][ks * 32 + kgrp * 8 + 4];
    f16x8 a;
    a[0] = (_Float16)u0.x; a[1] = (_Float16)u0.y; a[2] = (_Float16)u0.z; a[3] = (_Float16)u0.w;
    a[4] = (_Float16)u1.x; a[5] = (_Float16)u1.y; a[6] = (_Float16)u1.z; a[7] = (_Float16)u1.w;
    afr[ks] = a;
  }

  f32x4 acc1[8], acc2[8];
#pragma unroll
  for (int t = 0; t < 8; ++t) {
    acc1[t] = (f32x4){0.f, 0.f, 0.f, 0.f};
    acc2[t] = (f32x4){0.f, 0.f, 0.f, 0.f};
  }
#pragma unroll
  for (int ks = 0; ks < 4; ++ks)
#pragma unroll
    for (int t = 0; t < 8; ++t) {
      int boff = (t * 16 + sub) * 128 + ks * 32 + kgrp * 8;
      f16x8 b1 = *(const f16x8*)&W1T[boff];
      acc1[t] = __builtin_amdgcn_mfma_f32_16x16x32_f16(afr[ks], b1, acc1[t], 0, 0, 0);
      f16x8 b2 = *(const f16x8*)&W2T[boff];
      acc2[t] = __builtin_amdgcn_mfma_f32_16x16x32_f16(afr[ks], b2, acc2[t], 0, 0, 0);
    }

  float bb1[8], bb2[8];
#pragma unroll
  for (int t = 0; t < 8; ++t) {
    int c = t * 16 + sub;
    bb1[t] = b1v[c];
    bb2[t] = b2v[c];
  }

  // epilogue in MFMA lane layout; z-dots and hh from EXACT fp32 h in Als
#pragma unroll
  for (int r = 0; r < 4; ++r) {
    int rl = w * 16 + kgrp * 4 + r;
    long m = mbase + rl;
    float p1 = 0.f, p3 = 0.f, q1 = 0.f, q3 = 0.f;
    if (m < M) {
#pragma unroll
      for (int t = 0; t < 8; ++t) {
        int c = t * 16 + sub;
        float a = Als[rl][c];
        B1hh[m * 128 + c] = f2bf(acc1[t][r] + bb1[t]);
        B2hh[m * 128 + c] = f2bf(acc2[t][r] + bb2[t]);
        hh[m * 128 + c] = f2bf(a);
        p1 += a * cvec[c];
        p3 += a * cvec[256 + c];
        q1 += a * cvec[384 + c];
        q3 += a * cvec[640 + c];
      }
    }
#pragma unroll
    for (int mk = 1; mk < 16; mk <<= 1) {
      p1 += __shfl_xor(p1, mk); p3 += __shfl_xor(p3, mk);
      q1 += __shfl_xor(q1, mk); q3 += __shfl_xor(q3, mk);
    }
    if (m < M && sub == 0) { zs1[m] = p1; zs3[m] = p3; ze1[m] = q1; ze3[m] = q3; }
  }
}

// ---------------- K2: fused edge kernel (fp16 MFMA, fp16 LDS, bf16 gathers) ----------------
__global__ __launch_bounds__(256) void k_edge(const float* __restrict__ e,
                                              const _Float16* __restrict__ WT,
                                              const float* __restrict__ bias,
                                              const unsigned short* __restrict__ B1hh,
                                              const unsigned short* __restrict__ B2hh,
                                              const int* __restrict__ src, const int* __restrict__ dst,
                                              const float* __restrict__ cs2, const float* __restrict__ ce2,
                                              float* __restrict__ eout, unsigned short* __restrict__ ejh,
                                              float* __restrict__ zs2, float* __restrict__ ze2, int M) {
  __shared__ _Float16 Els[64][136];  // 17.4KB; row stride 272B = 68 dwords % 32 = 4
  int tid = threadIdx.x;
  int lane = tid & 63, w = tid >> 6;
  int kgrp = lane >> 4, sub = lane & 15;
  long mbase = (long)blockIdx.x * 64;
#pragma unroll
  for (int it = 0; it < 8; ++it) {
    int idx = tid + it * 256;
    int r = idx >> 5, cv = idx & 31;
    long m = mbase + r;
    float4 v = make_float4(0.f, 0.f, 0.f, 0.f);
    if (m < M) v = *(const float4*)&e[m * 128 + 4 * cv];
    f16x4 hv;
    hv[0] = (_Float16)v.x; hv[1] = (_Float16)v.y;
    hv[2] = (_Float16)v.z; hv[3] = (_Float16)v.w;
    *(f16x4*)&Els[r][4 * cv] = hv;
  }
  __syncthreads();

  int arow = w * 16 + sub;
  f16x8 afr[4];
#pragma unroll
  for (int ks = 0; ks < 4; ++ks)
    afr[ks] = *(const f16x8*)&Els[arow][ks * 32 + kgrp * 8];

  f32x4 acc[8];
#pragma unroll
  for (int t = 0; t < 8; ++t) acc[t] = (f32x4){0.f, 0.f, 0.f, 0.f};
#pragma unroll
  for (int ks = 0; ks < 4; ++ks)
#pragma unroll
    for (int t = 0; t < 8; ++t) {
      f16x8 b = *(const f16x8*)&WT[(t * 16 + sub) * 128 + ks * 32 + kgrp * 8];
      acc[t] = __builtin_amdgcn_mfma_f32_16x16x32_f16(afr[ks], b, acc[t], 0, 0, 0);
    }

  float bb[8], cs[8], ce[8];
#pragma unroll
  for (int t = 0; t < 8; ++t) {
    int c = t * 16 + sub;
    bb[t] = bias[c];
    cs[t] = cs2[c];
    ce[t] = ce2[c];
  }

  // epilogue in MFMA lane layout: lane owns rows w*16+kgrp*4+r, cols t*16+sub
#pragma unroll
  for (int r = 0; r < 4; ++r) {
    int rl = w * 16 + kgrp * 4 + r;
    long m = mbase + rl;
    float ps = 0.f, pe = 0.f;
    if (m < M) {
      int s = src[m], dv = dst[m];
      const unsigned short* b1p = B1hh + (long)s * 128;
      const unsigned short* b2p = B2hh + (long)dv * 128;
#pragma unroll
      for (int t = 0; t < 8; ++t) {
        int c = t * 16 + sub;
        float o = fmaxf(acc[t][r] + bb[t] + bf2f(b1p[c]) + bf2f(b2p[c]), 0.f) + (float)Els[rl][c];
        eout[m * 128 + c] = o;
        ejh[m * 128 + c] = f2bf(o);
        ps += o * cs[t];
        pe += o * ce[t];
      }
    }
#pragma unroll
    for (int mk = 1; mk < 16; mk <<= 1) {
      ps += __shfl_xor(ps, mk);
      pe += __shfl_xor(pe, mk);
    }
    if (m < M && sub == 0) { zs2[m] = ps; ze2[m] = pe; }
  }
}

// ---------------- CSR build ----------------
__global__ void k_hist(const int* __restrict__ src, const int* __restrict__ dst,
                       int* __restrict__ cntf, int* __restrict__ cntr, int E) {
  int e = blockIdx.x * 256 + threadIdx.x;
  if (e < E) {
    atomicAdd(&cntf[dst[e]], 1);
    atomicAdd(&cntr[src[e]], 1);
  }
}

__global__ __launch_bounds__(1024) void k_scan(const int* __restrict__ cntf,
                                               const int* __restrict__ cntr,
                                               int* __restrict__ offf, int* __restrict__ offr, int n) {
  __shared__ int part[1024];
  int tid = threadIdx.x;
  for (int pass = 0; pass < 2; ++pass) {
    const int* cnt = pass ? cntr : cntf;
    int* off = pass ? offr : offf;
    int per = (n + 1023) >> 10;
    int beg = tid * per; if (beg > n) beg = n;
    int end = beg + per; if (end > n) end = n;
    int s = 0;
    for (int i = beg; i < end; ++i) s += cnt[i];
    part[tid] = s;
    __syncthreads();
    for (int o = 1; o < 1024; o <<= 1) {
      int vv = (tid >= o) ? part[tid - o] : 0;
      __syncthreads();
      part[tid] += vv;
      __syncthreads();
    }
    int run = tid ? part[tid - 1] : 0;
    for (int i = beg; i < end; ++i) { off[i] = run; run += cnt[i]; }
    if (tid == 1023) off[n] = part[1023];
    __syncthreads();
  }
}

__global__ void k_fill(const int* __restrict__ src, const int* __restrict__ dst,
                       const int* __restrict__ offf, const int* __restrict__ offr,
                       int* __restrict__ curf, int* __restrict__ curr,
                       int* __restrict__ eidf, int* __restrict__ eidr, int E) {
  int e = blockIdx.x * 256 + threadIdx.x;
  if (e >= E) return;
  int d = dst[e];
  int p = atomicAdd(&curf[d], 1);
  eidf[offf[d] + p] = e;
  int s = src[e];
  p = atomicAdd(&curr[s], 1);
  eidr[offr[s] + p] = e;
}

// ---------------- K5: scores in sorted order ----------------
__global__ void k_scores(const int* __restrict__ src, const int* __restrict__ dst,
                         const int* __restrict__ eidf, const int* __restrict__ eidr,
                         const float* __restrict__ zs1, const float* __restrict__ zs2,
                         const float* __restrict__ zs3, const float* __restrict__ ze1,
                         const float* __restrict__ ze2, const float* __restrict__ ze3,
                         float* __restrict__ sf, float* __restrict__ sef,
                         float* __restrict__ sr, float* __restrict__ ser, int E) {
  int p = blockIdx.x * 256 + threadIdx.x;
  if (p >= E) return;
  {
    int e = eidf[p];
    int s = src[e], d = dst[e];
    float z2 = zs2[e], ze2v = ze2[e];
    sf[p] = lrelu(zs1[s] + z2 + zs3[d]);
    sef[p] = lrelu(ze1[s] + ze2v + ze3[d]);
  }
  {
    int e = eidr[p];
    int s = src[e], d = dst[e];
    float z2 = zs2[e], ze2v = ze2[e];
    sr[p] = lrelu(zs1[d] + z2 + zs3[s]);
    ser[p] = lrelu(ze1[d] + ze2v + ze3[s]);
  }
}

// ---------------- K6: softmax+aggregate (4x unrolled weight pass, f16 out) ----------------
__device__ inline float wred_max64(float v) {
#pragma unroll
  for (int mk = 32; mk; mk >>= 1) v = fmaxf(v, __shfl_xor(v, mk));
  return v;
}
__device__ inline float wred_sum64(float v) {
#pragma unroll
  for (int mk = 32; mk; mk >>= 1) v += __shfl_xor(v, mk);
  return v;
}

__global__ __launch_bounds__(256) void k_agg4(const int* __restrict__ offf, const int* __restrict__ eidf,
                                              const int* __restrict__ offr, const int* __restrict__ eidr,
                                              const int* __restrict__ src, const int* __restrict__ dst,
                                              const float* __restrict__ sf, const float* __restrict__ sef,
                                              const float* __restrict__ sr, const float* __restrict__ ser,
                                              const unsigned short* __restrict__ hh,
                                              const unsigned short* __restrict__ ejh,
                                              _Float16* __restrict__ agg2, int n) {
  int gw = blockIdx.x * 4 + (threadIdx.x >> 6);
  int lane = threadIdx.x & 63;
  if (gw >= 2 * n) return;
  int dir = gw & 1;
  int v = gw >> 1;
  const int* off = dir ? offr : offf;
  const int* eid = dir ? eidr : eidf;
  const float* sc  = dir ? sr  : sf;
  const float* sce = dir ? ser : sef;
  const int* nbr = dir ? dst : src;
  int s0 = off[v], s1 = off[v + 1];
  float m1 = -1e30f, m2 = -1e30f;
  for (int i = s0 + lane; i < s1; i += 64) {
    m1 = fmaxf(m1, sc[i]);
    m2 = fmaxf(m2, sce[i]);
  }
  m1 = wred_max64(m1); m2 = wred_max64(m2);
  float d1 = 0.f, d2 = 0.f;
  for (int i = s0 + lane; i < s1; i += 64) {
    d1 += __expf(sc[i] - m1);
    d2 += __expf(sce[i] - m2);
  }
  d1 = wred_sum64(d1); d2 = wred_sum64(d2);
  float i1 = (s1 > s0) ? 1.f / d1 : 0.f;
  float i2 = (s1 > s0) ? 1.f / d2 : 0.f;
  float aH0 = 0.f, aH1 = 0.f, aE0 = 0.f, aE1 = 0.f;
  int i = s0;
  for (; i + 3 < s1; i += 4) {
    int eA = eid[i], eB = eid[i + 1], eC = eid[i + 2], eD = eid[i + 3];
    int nA = nbr[eA], nB = nbr[eB], nC = nbr[eC], nD = nbr[eD];
    unsigned hpA = *(const unsigned*)&hh[(long)nA * 128 + 2 * lane];
    unsigned epA = *(const unsigned*)&ejh[(long)eA * 128 + 2 * lane];
    unsigned hpB = *(const unsigned*)&hh[(long)nB * 128 + 2 * lane];
    unsigned epB = *(const unsigned*)&ejh[(long)eB * 128 + 2 * lane];
    unsigned hpC = *(const unsigned*)&hh[(long)nC * 128 + 2 * lane];
    unsigned epC = *(const unsigned*)&ejh[(long)eC * 128 + 2 * lane];
    unsigned hpD = *(const unsigned*)&hh[(long)nD * 128 + 2 * lane];
    unsigned epD = *(const unsigned*)&ejh[(long)eD * 128 + 2 * lane];
    float w1A = __expf(sc[i] - m1) * i1,     w2A = __expf(sce[i] - m2) * i2;
    float w1B = __expf(sc[i + 1] - m1) * i1, w2B = __expf(sce[i + 1] - m2) * i2;
    float w1C = __expf(sc[i + 2] - m1) * i1, w2C = __expf(sce[i + 2] - m2) * i2;
    float w1D = __expf(sc[i + 3] - m1) * i1, w2D = __expf(sce[i + 3] - m2) * i2;
    aH0 += w1A * bf2f((unsigned short)(hpA & 0xFFFFu)) + w1B * bf2f((unsigned short)(hpB & 0xFFFFu))
         + w1C * bf2f((unsigned short)(hpC & 0xFFFFu)) + w1D * bf2f((unsigned short)(hpD & 0xFFFFu));
    aH1 += w1A * bf2f((unsigned short)(hpA >> 16)) + w1B * bf2f((unsigned short)(hpB >> 16))
         + w1C * bf2f((unsigned short)(hpC >> 16)) + w1D * bf2f((unsigned short)(hpD >> 16));
    aE0 += w2A * bf2f((unsigned short)(epA & 0xFFFFu)) + w2B * bf2f((unsigned short)(epB & 0xFFFFu))
         + w2C * bf2f((unsigned short)(epC & 0xFFFFu)) + w2D * bf2f((unsigned short)(epD & 0xFFFFu));
    aE1 += w2A * bf2f((unsigned short)(epA >> 16)) + w2B * bf2f((unsigned short)(epB >> 16))
         + w2C * bf2f((unsigned short)(epC >> 16)) + w2D * bf2f((unsigned short)(epD >> 16));
  }
  for (; i < s1; ++i) {
    int e_ = eid[i];
    int nb = nbr[e_];
    float w1 = __expf(sc[i] - m1) * i1;
    float w2 = __expf(sce[i] - m2) * i2;
    unsigned hp = *(const unsigned*)&hh[(long)nb * 128 + 2 * lane];
    unsigned ep = *(const unsigned*)&ejh[(long)e_ * 128 + 2 * lane];
    aH0 += w1 * bf2f((unsigned short)(hp & 0xFFFFu));
    aH1 += w1 * bf2f((unsigned short)(hp >> 16));
    aE0 += w2 * bf2f((unsigned short)(ep & 0xFFFFu));
    aE1 += w2 * bf2f((unsigned short)(ep >> 16));
  }
  _Float16* dstp = agg2 + ((long)dir * n + v) * 256;
  *(f16x2*)&dstp[2 * lane] = (f16x2){(_Float16)aH0, (_Float16)aH1};
  *(f16x2*)&dstp[128 + 2 * lane] = (f16x2){(_Float16)aE0, (_Float16)aE1};
}

// ---------------- K7: mix GEMM (fp16 MFMA) + LayerNorm + relu + residual ----------------
__global__ __launch_bounds__(256) void k_mix_ln(const _Float16* __restrict__ A,   // agg2 [2][M][256] f16
                                                const _Float16* __restrict__ McT, // [128][256] fp16
                                                const float* __restrict__ bias,   // bmix (x2)
                                                const float* __restrict__ h,
                                                const float* __restrict__ g,
                                                const float* __restrict__ bn,
                                                float* __restrict__ outp, int M) {
  __shared__ _Float16 Als[64][264];  // stride 528B = 132 dwords % 32 = 4 -> conflict-free
  int tid = threadIdx.x;
  int lane = tid & 63, w = tid >> 6;
  int kgrp = lane >> 4, sub = lane & 15;
  long mbase = (long)blockIdx.x * 64;
  const _Float16* A2 = A + (long)M * 256;
#pragma unroll
  for (int it = 0; it < 8; ++it) {
    int idx = tid + it * 256;      // 0..2047
    int r = idx >> 5, c8 = (idx & 31) * 8;
    long m = mbase + r;
    f16x8 hv = (f16x8){0, 0, 0, 0, 0, 0, 0, 0};
    if (m < M) {
      f16x8 v1 = *(const f16x8*)&A[m * 256 + c8];
      f16x8 v2 = *(const f16x8*)&A2[m * 256 + c8];
#pragma unroll
      for (int j = 0; j < 8; ++j) hv[j] = (_Float16)((float)v1[j] + (float)v2[j]);
    }
    *(f16x8*)&Als[r][c8] = hv;
  }
  __syncthreads();

  int arow = w * 16 + sub;
  f32x4 acc[8];
#pragma unroll
  for (int t = 0; t < 8; ++t) acc[t] = (f32x4){0.f, 0.f, 0.f, 0.f};
#pragma unroll
  for (int ks = 0; ks < 8; ++ks) {
    f16x8 a = *(const f16x8*)&Als[arow][ks * 32 + kgrp * 8];
#pragma unroll
    for (int t = 0; t < 8; ++t) {
      f16x8 b = *(const f16x8*)&McT[(t * 16 + sub) * 256 + ks * 32 + kgrp * 8];
      acc[t] = __builtin_amdgcn_mfma_f32_16x16x32_f16(a, b, acc[t], 0, 0, 0);
    }
  }

  float bb[8], gv[8], bv[8];
#pragma unroll
  for (int t = 0; t < 8; ++t) {
    int c = t * 16 + sub;
    bb[t] = 2.f * bias[c];
    gv[t] = g[c];
    bv[t] = bn[c];
  }

  // epilogue: lane owns rows w*16+kgrp*4+r, cols t*16+sub; row group = 16 sub-lanes
#pragma unroll
  for (int r = 0; r < 4; ++r) {
    int rl = w * 16 + kgrp * 4 + r;
    long m = mbase + rl;
    float x[8];
    float s = 0.f, q = 0.f;
#pragma unroll
    for (int t = 0; t < 8; ++t) {
      x[t] = acc[t][r] + bb[t];
      s += x[t];
      q += x[t] * x[t];
    }
#pragma unroll
    for (int mk = 1; mk < 16; mk <<= 1) {
      s += __shfl_xor(s, mk);
      q += __shfl_xor(q, mk);
    }
    float mu = s * (1.f / 128.f);
    float var = q * (1.f / 128.f) - mu * mu;
    float rstd = rsqrtf(var + 1e-5f);
    if (m < M) {
      const float* hp = h + m * 128;
#pragma unroll
      for (int t = 0; t < 8; ++t) {
        int c = t * 16 + sub;
        outp[m * 128 + c] = fmaxf((x[t] - mu) * rstd * gv[t] + bv[t], 0.f) + hp[c];
      }
    }
  }
}

extern "C" void kernel_launch(void* const* d_in, const int* in_sizes, int n_in,
                              void* d_out, int out_size, void* d_ws, size_t ws_size,
                              hipStream_t stream) {
  const float* h = (const float*)d_in[0];
  const float* e = (const float*)d_in[1];
  const int* src = (const int*)d_in[2];
  const int* dst = (const int*)d_in[3];
  const float* Wfc = (const float*)d_in[4];
  const float* Wfce = (const float*)d_in[5];
  const float* aat = (const float*)d_in[6];
  const float* aate = (const float*)d_in[7];
  const float* WB1 = (const float*)d_in[8];
  const float* bB1 = (const float*)d_in[9];
  const float* WB2 = (const float*)d_in[10];
  const float* bB2 = (const float*)d_in[11];
  const float* WB3 = (const float*)d_in[12];
  const float* bB3 = (const float*)d_in[13];
  const float* Wmix = (const float*)d_in[14];
  const float* bmix = (const float*)d_in[15];
  const float* lng = (const float*)d_in[16];
  const float* lnb = (const float*)d_in[17];
  int n = in_sizes[0] / 128;
  int E = in_sizes[1] / 128;

  float* hout = (float*)d_out;
  float* eout = (float*)d_out + (size_t)n * 128;

  char* w = (char*)d_ws;
  auto alloc = [&](size_t bytes) {
    void* p = w;
    w += (bytes + 255) / 256 * 256;
    return p;
  };
  unsigned short* B1hh = (unsigned short*)alloc((size_t)n * 128 * 2);
  unsigned short* B2hh = (unsigned short*)alloc((size_t)n * 128 * 2);
  _Float16* agg2 = (_Float16*)alloc((size_t)n * 512 * 2);
  float* zs1 = (float*)alloc((size_t)n * 4);
  float* zs3 = (float*)alloc((size_t)n * 4);
  float* ze1 = (float*)alloc((size_t)n * 4);
  float* ze3 = (float*)alloc((size_t)n * 4);
  float* zs2 = (float*)alloc((size_t)E * 4);
  float* ze2 = (float*)alloc((size_t)E * 4);
  float* sf = (float*)alloc((size_t)E * 4);
  float* sef = (float*)alloc((size_t)E * 4);
  float* sr = (float*)alloc((size_t)E * 4);
  float* ser = (float*)alloc((size_t)E * 4);
  float* cvec = (float*)alloc(768 * 4);
  _Float16* WT = (_Float16*)alloc(128 * 128 * 2);
  _Float16* W1T = (_Float16*)alloc(128 * 128 * 2);
  _Float16* W2T = (_Float16*)alloc(128 * 128 * 2);
  _Float16* McT = (_Float16*)alloc(128 * 256 * 2);
  int* offf = (int*)alloc((size_t)(n + 1) * 4);
  int* offr = (int*)alloc((size_t)(n + 1) * 4);
  size_t curpad = ((size_t)n * 4 + 255) / 256 * 256;
  int* curf = (int*)alloc((size_t)n * 4);
  int* curr = (int*)alloc((size_t)n * 4);
  int* eidf = (int*)alloc((size_t)E * 4);
  int* eidr = (int*)alloc((size_t)E * 4);
  unsigned short* ejh = (unsigned short*)alloc((size_t)E * 128 * 2);
  unsigned short* hh = (unsigned short*)alloc((size_t)n * 128 * 2);

  hipMemsetAsync(curf, 0, curpad * 2, stream);  // curf + curr (adjacent)

  k_combine<<<262, 128, 0, stream>>>(Wfc, Wfce, Wmix, aat, aate, McT, cvec);
  k_wt3<<<192, 256, 0, stream>>>(WB3, WB1, WB2, WT, W1T, W2T);
  k_gemm_dual<<<(n + 63) / 64, 256, 0, stream>>>(h, W1T, bB1, W2T, bB2, cvec, B1hh, B2hh, hh,
                                                 zs1, zs3, ze1, ze3, n);
  k_hist<<<(E + 255) / 256, 256, 0, stream>>>(src, dst, curf, curr, E);
  k_scan<<<1, 1024, 0, stream>>>(curf, curr, offf, offr, n);
  hipMemsetAsync(curf, 0, curpad * 2, stream);
  k_fill<<<(E + 255) / 256, 256, 0, stream>>>(src, dst, offf, offr, curf, curr, eidf, eidr, E);
  k_edge<<<(E + 63) / 64, 256, 0, stream>>>(e, WT, bB3, B1hh, B2hh, src, dst,
                                            cvec + 128, cvec + 512, eout, ejh, zs2, ze2, E);
  k_scores<<<(E + 255) / 256, 256, 0, stream>>>(src, dst, eidf, eidr, zs1, zs2, zs3, ze1, ze2, ze3,
                                                sf, sef, sr, ser, E);
  k_agg4<<<(2 * n + 3) / 4, 256, 0, stream>>>(offf, eidf, offr, eidr, src, dst, sf, sef, sr, ser,
                                              hh, ejh, agg2, n);
  k_mix_ln<<<(n + 63) / 64, 256, 0, stream>>>(agg2, McT, bmix, h, lng, lnb, hout, n);
}

// Round 20
// 1045.031 us; speedup vs baseline: 1.1977x; 1.0332x over previous
//
#include <hip/hip_runtime.h>
#include <hip/hip_bf16.h>

// SymGAT fused layer. Round 20: k_agg de-chained.
//  - ejh written in forward-CSR order (k_edge scatters rows via posf; single
//    copy, volume-neutral). Forward aggregation reads ejh sequentially.
//  - k_scores emits flat arrays nf/nr (neighbor per CSR position) and er2
//    (reverse position -> forward ejh row): k_agg weight pass has no
//    dependent index loads left.
//  - everything else identical to round-19 baseline (1080us).

typedef _Float16 f16x8 __attribute__((ext_vector_type(8)));
typedef _Float16 f16x4 __attribute__((ext_vector_type(4)));
typedef _Float16 f16x2 __attribute__((ext_vector_type(2)));
typedef float f32x4 __attribute__((ext_vector_type(4)));

__device__ inline float lrelu(float x) { return x > 0.f ? x : 0.01f * x; }

__device__ inline unsigned short f2bf(float f) {  // RNE float->bf16
  unsigned u = __float_as_uint(f);
  unsigned r = (u + 0x7FFFu + ((u >> 16) & 1u)) >> 16;
  return (unsigned short)r;
}
__device__ inline float bf2f(unsigned short us) {
  return __uint_as_float(((unsigned)us) << 16);
}

// ---------------- K0: weight combos (McT written fp16 transposed) ----------------
__global__ void k_combine(const float* __restrict__ Wfc, const float* __restrict__ Wfce,
                          const float* __restrict__ Wmix, const float* __restrict__ aat,
                          const float* __restrict__ aate, _Float16* __restrict__ McT,
                          float* __restrict__ cvec) {
  int b = blockIdx.x, j = threadIdx.x;
  if (b < 256) {
    const float* Arow;
    const float* Wm;
    if (b < 128) { Arow = Wfc + b * 128; Wm = Wmix; }
    else         { Arow = Wfce + (b - 128) * 128; Wm = Wmix + 128 * 128; }
    float acc = 0.f;
    for (int t = 0; t < 128; ++t) acc += Arow[t] * Wm[t * 128 + j];
    McT[j * 256 + b] = (_Float16)acc;   // transposed fp16
  } else {
    int idx = b - 256;
    const float* W; const float* a;
    switch (idx) {
      case 0: W = Wfc;  a = aat;        break;  // c_s1 @ cvec+0
      case 1: W = Wfce; a = aat + 128;  break;  // c_s2 @ cvec+128
      case 2: W = Wfc;  a = aat + 256;  break;  // c_s3 @ cvec+256
      case 3: W = Wfc;  a = aate;       break;  // c_e1 @ cvec+384
      case 4: W = Wfce; a = aate + 128; break;  // c_e2 @ cvec+512
      default: W = Wfc; a = aate + 256; break;  // c_e3 @ cvec+640
    }
    float acc = 0.f;
    for (int t = 0; t < 128; ++t) acc += W[j * 128 + t] * a[t];
    cvec[idx * 128 + j] = acc;
  }
}

// ---------------- WT3: {W_B3, W_B1, W_B2} -> fp16 transposed ----------------
__global__ __launch_bounds__(256) void k_wt3(const float* __restrict__ W3,
                                             const float* __restrict__ W1,
                                             const float* __restrict__ W2,
                                             _Float16* __restrict__ WT,
                                             _Float16* __restrict__ W1T,
                                             _Float16* __restrict__ W2T) {
  int idx = blockIdx.x * 256 + threadIdx.x;  // 49152 total
  int which = idx >> 14;
  int r = idx & 16383;
  int c = r >> 7, k = r & 127;
  const float* s = (which == 0) ? W3 : (which == 1) ? W1 : W2;
  _Float16* d = (which == 0) ? WT : (which == 1) ? W1T : W2T;
  d[r] = (_Float16)s[k * 128 + c];
}

// ---------------- K1: dual GEMM (fp16 MFMA) + nodevec dots + hh shadow ----------------
__global__ __launch_bounds__(256) void k_gemm_dual(const float* __restrict__ A,
                                                   const _Float16* __restrict__ W1T,
                                                   const float* __restrict__ b1v,
                                                   const _Float16* __restrict__ W2T,
                                                   const float* __restrict__ b2v,
                                                   const float* __restrict__ cvec,
                                                   unsigned short* __restrict__ B1hh,
                                                   unsigned short* __restrict__ B2hh,
                                                   unsigned short* __restrict__ hh,
                                                   float* __restrict__ zs1, float* __restrict__ zs3,
                                                   float* __restrict__ ze1, float* __restrict__ ze3,
                                                   int M) {
  __shared__ float Als[64][132];
  int tid = threadIdx.x;
  int lane = tid & 63, w = tid >> 6;
  int kgrp = lane >> 4, sub = lane & 15;
  long mbase = (long)blockIdx.x * 64;
#pragma unroll
  for (int it = 0; it < 8; ++it) {
    int idx = tid + it * 256;
    int r = idx >> 5, cv = idx & 31;
    long m = mbase + r;
    float4 v = make_float4(0.f, 0.f, 0.f, 0.f);
    if (m < M) v = *(const float4*)&A[m * 128 + 4 * cv];
    *(float4*)&Als[r][4 * cv] = v;
  }
  __syncthreads();

  int arow = w * 16 + sub;
  f16x8 afr[4];
#pragma unroll
  for (int ks = 0; ks < 4; ++ks) {
    float4 u0 = *(const float4*)&Als[arow][ks * 32 + kgrp * 8];
    float4 u1 = *(const float4*)&Als[arow][ks * 32 + kgrp * 8 + 4];
    f16x8 a;
    a[0] = (_Float16)u0.x; a[1] = (_Float16)u0.y; a[2] = (_Float16)u0.z; a[3] = (_Float16)u0.w;
    a[4] = (_Float16)u1.x; a[5] = (_Float16)u1.y; a[6] = (_Float16)u1.z; a[7] = (_Float16)u1.w;
    afr[ks] = a;
  }

  f32x4 acc1[8], acc2[8];
#pragma unroll
  for (int t = 0; t < 8; ++t) {
    acc1[t] = (f32x4){0.f, 0.f, 0.f, 0.f};
    acc2[t] = (f32x4){0.f, 0.f, 0.f, 0.f};
  }
#pragma unroll
  for (int ks = 0; ks < 4; ++ks)
#pragma unroll
    for (int t = 0; t < 8; ++t) {
      int boff = (t * 16 + sub) * 128 + ks * 32 + kgrp * 8;
      f16x8 b1 = *(const f16x8*)&W1T[boff];
      acc1[t] = __builtin_amdgcn_mfma_f32_16x16x32_f16(afr[ks], b1, acc1[t], 0, 0, 0);
      f16x8 b2 = *(const f16x8*)&W2T[boff];
      acc2[t] = __builtin_amdgcn_mfma_f32_16x16x32_f16(afr[ks], b2, acc2[t], 0, 0, 0);
    }

  float bb1[8], bb2[8];
#pragma unroll
  for (int t = 0; t < 8; ++t) {
    int c = t * 16 + sub;
    bb1[t] = b1v[c];
    bb2[t] = b2v[c];
  }

  // epilogue in MFMA lane layout; z-dots and hh from EXACT fp32 h in Als
#pragma unroll
  for (int r = 0; r < 4; ++r) {
    int rl = w * 16 + kgrp * 4 + r;
    long m = mbase + rl;
    float p1 = 0.f, p3 = 0.f, q1 = 0.f, q3 = 0.f;
    if (m < M) {
#pragma unroll
      for (int t = 0; t < 8; ++t) {
        int c = t * 16 + sub;
        float a = Als[rl][c];
        B1hh[m * 128 + c] = f2bf(acc1[t][r] + bb1[t]);
        B2hh[m * 128 + c] = f2bf(acc2[t][r] + bb2[t]);
        hh[m * 128 + c] = f2bf(a);
        p1 += a * cvec[c];
        p3 += a * cvec[256 + c];
        q1 += a * cvec[384 + c];
        q3 += a * cvec[640 + c];
      }
    }
#pragma unroll
    for (int mk = 1; mk < 16; mk <<= 1) {
      p1 += __shfl_xor(p1, mk); p3 += __shfl_xor(p3, mk);
      q1 += __shfl_xor(q1, mk); q3 += __shfl_xor(q3, mk);
    }
    if (m < M && sub == 0) { zs1[m] = p1; zs3[m] = p3; ze1[m] = q1; ze3[m] = q3; }
  }
}

// ---------------- K2: fused edge kernel (fp16 MFMA; ejh scattered to fwd-CSR) ----------------
__global__ __launch_bounds__(256) void k_edge(const float* __restrict__ e,
                                              const _Float16* __restrict__ WT,
                                              const float* __restrict__ bias,
                                              const unsigned short* __restrict__ B1hh,
                                              const unsigned short* __restrict__ B2hh,
                                              const int* __restrict__ src, const int* __restrict__ dst,
                                              const int* __restrict__ posf,
                                              const float* __restrict__ cs2, const float* __restrict__ ce2,
                                              float* __restrict__ eout, unsigned short* __restrict__ ejh,
                                              float* __restrict__ zs2, float* __restrict__ ze2, int M) {
  __shared__ _Float16 Els[64][136];  // 17.4KB; row stride 272B = 68 dwords % 32 = 4
  int tid = threadIdx.x;
  int lane = tid & 63, w = tid >> 6;
  int kgrp = lane >> 4, sub = lane & 15;
  long mbase = (long)blockIdx.x * 64;
#pragma unroll
  for (int it = 0; it < 8; ++it) {
    int idx = tid + it * 256;
    int r = idx >> 5, cv = idx & 31;
    long m = mbase + r;
    float4 v = make_float4(0.f, 0.f, 0.f, 0.f);
    if (m < M) v = *(const float4*)&e[m * 128 + 4 * cv];
    f16x4 hv;
    hv[0] = (_Float16)v.x; hv[1] = (_Float16)v.y;
    hv[2] = (_Float16)v.z; hv[3] = (_Float16)v.w;
    *(f16x4*)&Els[r][4 * cv] = hv;
  }
  __syncthreads();

  int arow = w * 16 + sub;
  f16x8 afr[4];
#pragma unroll
  for (int ks = 0; ks < 4; ++ks)
    afr[ks] = *(const f16x8*)&Els[arow][ks * 32 + kgrp * 8];

  f32x4 acc[8];
#pragma unroll
  for (int t = 0; t < 8; ++t) acc[t] = (f32x4){0.f, 0.f, 0.f, 0.f};
#pragma unroll
  for (int ks = 0; ks < 4; ++ks)
#pragma unroll
    for (int t = 0; t < 8; ++t) {
      f16x8 b = *(const f16x8*)&WT[(t * 16 + sub) * 128 + ks * 32 + kgrp * 8];
      acc[t] = __builtin_amdgcn_mfma_f32_16x16x32_f16(afr[ks], b, acc[t], 0, 0, 0);
    }

  float bb[8], cs[8], ce[8];
#pragma unroll
  for (int t = 0; t < 8; ++t) {
    int c = t * 16 + sub;
    bb[t] = bias[c];
    cs[t] = cs2[c];
    ce[t] = ce2[c];
  }

  // epilogue in MFMA lane layout: lane owns rows w*16+kgrp*4+r, cols t*16+sub
#pragma unroll
  for (int r = 0; r < 4; ++r) {
    int rl = w * 16 + kgrp * 4 + r;
    long m = mbase + rl;
    float ps = 0.f, pe = 0.f;
    if (m < M) {
      int s = src[m], dv = dst[m];
      long pf = posf[m];
      const unsigned short* b1p = B1hh + (long)s * 128;
      const unsigned short* b2p = B2hh + (long)dv * 128;
#pragma unroll
      for (int t = 0; t < 8; ++t) {
        int c = t * 16 + sub;
        float o = fmaxf(acc[t][r] + bb[t] + bf2f(b1p[c]) + bf2f(b2p[c]), 0.f) + (float)Els[rl][c];
        eout[m * 128 + c] = o;
        ejh[pf * 128 + c] = f2bf(o);
        ps += o * cs[t];
        pe += o * ce[t];
      }
    }
#pragma unroll
    for (int mk = 1; mk < 16; mk <<= 1) {
      ps += __shfl_xor(ps, mk);
      pe += __shfl_xor(pe, mk);
    }
    if (m < M && sub == 0) { zs2[m] = ps; ze2[m] = pe; }
  }
}

// ---------------- CSR build ----------------
__global__ void k_hist(const int* __restrict__ src, const int* __restrict__ dst,
                       int* __restrict__ cntf, int* __restrict__ cntr, int E) {
  int e = blockIdx.x * 256 + threadIdx.x;
  if (e < E) {
    atomicAdd(&cntf[dst[e]], 1);
    atomicAdd(&cntr[src[e]], 1);
  }
}

__global__ __launch_bounds__(1024) void k_scan(const int* __restrict__ cntf,
                                               const int* __restrict__ cntr,
                                               int* __restrict__ offf, int* __restrict__ offr, int n) {
  __shared__ int part[1024];
  int tid = threadIdx.x;
  for (int pass = 0; pass < 2; ++pass) {
    const int* cnt = pass ? cntr : cntf;
    int* off = pass ? offr : offf;
    int per = (n + 1023) >> 10;
    int beg = tid * per; if (beg > n) beg = n;
    int end = beg + per; if (end > n) end = n;
    int s = 0;
    for (int i = beg; i < end; ++i) s += cnt[i];
    part[tid] = s;
    __syncthreads();
    for (int o = 1; o < 1024; o <<= 1) {
      int vv = (tid >= o) ? part[tid - o] : 0;
      __syncthreads();
      part[tid] += vv;
      __syncthreads();
    }
    int run = tid ? part[tid - 1] : 0;
    for (int i = beg; i < end; ++i) { off[i] = run; run += cnt[i]; }
    if (tid == 1023) off[n] = part[1023];
    __syncthreads();
  }
}

__global__ void k_fill(const int* __restrict__ src, const int* __restrict__ dst,
                       const int* __restrict__ offf, const int* __restrict__ offr,
                       int* __restrict__ curf, int* __restrict__ curr,
                       int* __restrict__ eidf, int* __restrict__ eidr,
                       int* __restrict__ posf, int* E_unused, int E) {
  int e = blockIdx.x * 256 + threadIdx.x;
  if (e >= E) return;
  int d = dst[e];
  int p = atomicAdd(&curf[d], 1);
  int qf = offf[d] + p;
  eidf[qf] = e;
  posf[e] = qf;
  int s = src[e];
  p = atomicAdd(&curr[s], 1);
  eidr[offr[s] + p] = e;
}

// ---------------- K5: scores in sorted order + flat nbr/row maps ----------------
__global__ void k_scores(const int* __restrict__ src, const int* __restrict__ dst,
                         const int* __restrict__ eidf, const int* __restrict__ eidr,
                         const int* __restrict__ posf,
                         const float* __restrict__ zs1, const float* __restrict__ zs2,
                         const float* __restrict__ zs3, const float* __restrict__ ze1,
                         const float* __restrict__ ze2, const float* __restrict__ ze3,
                         float* __restrict__ sf, float* __restrict__ sef,
                         float* __restrict__ sr, float* __restrict__ ser,
                         int* __restrict__ nf, int* __restrict__ nr,
                         int* __restrict__ er2, int E) {
  int p = blockIdx.x * 256 + threadIdx.x;
  if (p >= E) return;
  {
    int e = eidf[p];
    int s = src[e], d = dst[e];
    float z2 = zs2[e], ze2v = ze2[e];
    sf[p] = lrelu(zs1[s] + z2 + zs3[d]);
    sef[p] = lrelu(ze1[s] + ze2v + ze3[d]);
    nf[p] = s;
  }
  {
    int e = eidr[p];
    int s = src[e], d = dst[e];
    float z2 = zs2[e], ze2v = ze2[e];
    sr[p] = lrelu(zs1[d] + z2 + zs3[s]);
    ser[p] = lrelu(ze1[d] + ze2v + ze3[s]);
    nr[p] = d;
    er2[p] = posf[e];
  }
}

// ---------------- K6: softmax+aggregate (no dependent index loads) ----------------
__device__ inline float wred_max64(float v) {
#pragma unroll
  for (int mk = 32; mk; mk >>= 1) v = fmaxf(v, __shfl_xor(v, mk));
  return v;
}
__device__ inline float wred_sum64(float v) {
#pragma unroll
  for (int mk = 32; mk; mk >>= 1) v += __shfl_xor(v, mk);
  return v;
}

__global__ __launch_bounds__(256) void k_agg4(const int* __restrict__ offf,
                                              const int* __restrict__ offr,
                                              const int* __restrict__ nf, const int* __restrict__ nr,
                                              const int* __restrict__ er2,
                                              const float* __restrict__ sf, const float* __restrict__ sef,
                                              const float* __restrict__ sr, const float* __restrict__ ser,
                                              const unsigned short* __restrict__ hh,
                                              const unsigned short* __restrict__ ejh,
                                              _Float16* __restrict__ agg2, int n) {
  int gw = blockIdx.x * 4 + (threadIdx.x >> 6);
  int lane = threadIdx.x & 63;
  if (gw >= 2 * n) return;
  int dir = gw & 1;
  int v = gw >> 1;
  const int* off = dir ? offr : offf;
  const float* sc  = dir ? sr  : sf;
  const float* sce = dir ? ser : sef;
  const int* nbArr = dir ? nr : nf;
  int s0 = off[v], s1 = off[v + 1];
  float m1 = -1e30f, m2 = -1e30f;
  for (int i = s0 + lane; i < s1; i += 64) {
    m1 = fmaxf(m1, sc[i]);
    m2 = fmaxf(m2, sce[i]);
  }
  m1 = wred_max64(m1); m2 = wred_max64(m2);
  float d1 = 0.f, d2 = 0.f;
  for (int i = s0 + lane; i < s1; i += 64) {
    d1 += __expf(sc[i] - m1);
    d2 += __expf(sce[i] - m2);
  }
  d1 = wred_sum64(d1); d2 = wred_sum64(d2);
  float i1 = (s1 > s0) ? 1.f / d1 : 0.f;
  float i2 = (s1 > s0) ? 1.f / d2 : 0.f;
  float aH0 = 0.f, aH1 = 0.f, aE0 = 0.f, aE1 = 0.f;
  int i = s0;
  if (dir == 0) {
    for (; i + 3 < s1; i += 4) {
      int nA = nf[i], nB = nf[i + 1], nC = nf[i + 2], nD = nf[i + 3];
      unsigned hpA = *(const unsigned*)&hh[(long)nA * 128 + 2 * lane];
      unsigned epA = *(const unsigned*)&ejh[(long)i * 128 + 2 * lane];
      unsigned hpB = *(const unsigned*)&hh[(long)nB * 128 + 2 * lane];
      unsigned epB = *(const unsigned*)&ejh[(long)(i + 1) * 128 + 2 * lane];
      unsigned hpC = *(const unsigned*)&hh[(long)nC * 128 + 2 * lane];
      unsigned epC = *(const unsigned*)&ejh[(long)(i + 2) * 128 + 2 * lane];
      unsigned hpD = *(const unsigned*)&hh[(long)nD * 128 + 2 * lane];
      unsigned epD = *(const unsigned*)&ejh[(long)(i + 3) * 128 + 2 * lane];
      float w1A = __expf(sc[i] - m1) * i1,     w2A = __expf(sce[i] - m2) * i2;
      float w1B = __expf(sc[i + 1] - m1) * i1, w2B = __expf(sce[i + 1] - m2) * i2;
      float w1C = __expf(sc[i + 2] - m1) * i1, w2C = __expf(sce[i + 2] - m2) * i2;
      float w1D = __expf(sc[i + 3] - m1) * i1, w2D = __expf(sce[i + 3] - m2) * i2;
      aH0 += w1A * bf2f((unsigned short)(hpA & 0xFFFFu)) + w1B * bf2f((unsigned short)(hpB & 0xFFFFu))
           + w1C * bf2f((unsigned short)(hpC & 0xFFFFu)) + w1D * bf2f((unsigned short)(hpD & 0xFFFFu));
      aH1 += w1A * bf2f((unsigned short)(hpA >> 16)) + w1B * bf2f((unsigned short)(hpB >> 16))
           + w1C * bf2f((unsigned short)(hpC >> 16)) + w1D * bf2f((unsigned short)(hpD >> 16));
      aE0 += w2A * bf2f((unsigned short)(epA & 0xFFFFu)) + w2B * bf2f((unsigned short)(epB & 0xFFFFu))
           + w2C * bf2f((unsigned short)(epC & 0xFFFFu)) + w2D * bf2f((unsigned short)(epD & 0xFFFFu));
      aE1 += w2A * bf2f((unsigned short)(epA >> 16)) + w2B * bf2f((unsigned short)(epB >> 16))
           + w2C * bf2f((unsigned short)(epC >> 16)) + w2D * bf2f((unsigned short)(epD >> 16));
    }
    for (; i < s1; ++i) {
      int nb = nf[i];
      float w1 = __expf(sc[i] - m1) * i1;
      float w2 = __expf(sce[i] - m2) * i2;
      unsigned hp = *(const unsigned*)&hh[(long)nb * 128 + 2 * lane];
      unsigned ep = *(const unsigned*)&ejh[(long)i * 128 + 2 * lane];
      aH0 += w1 * bf2f((unsigned short)(hp & 0xFFFFu));
      aH1 += w1 * bf2f((unsigned short)(hp >> 16));
      aE0 += w2 * bf2f((unsigned short)(ep & 0xFFFFu));
      aE1 += w2 * bf2f((unsigned short)(ep >> 16));
    }
  } else {
    for (; i + 3 < s1; i += 4) {
      int nA = nr[i], nB = nr[i + 1], nC = nr[i + 2], nD = nr[i + 3];
      int rA = er2[i], rB = er2[i + 1], rC = er2[i + 2], rD = er2[i + 3];
      unsigned hpA = *(const unsigned*)&hh[(long)nA * 128 + 2 * lane];
      unsigned epA = *(const unsigned*)&ejh[(long)rA * 128 + 2 * lane];
      unsigned hpB = *(const unsigned*)&hh[(long)nB * 128 + 2 * lane];
      unsigned epB = *(const unsigned*)&ejh[(long)rB * 128 + 2 * lane];
      unsigned hpC = *(const unsigned*)&hh[(long)nC * 128 + 2 * lane];
      unsigned epC = *(const unsigned*)&ejh[(long)rC * 128 + 2 * lane];
      unsigned hpD = *(const unsigned*)&hh[(long)nD * 128 + 2 * lane];
      unsigned epD = *(const unsigned*)&ejh[(long)rD * 128 + 2 * lane];
      float w1A = __expf(sc[i] - m1) * i1,     w2A = __expf(sce[i] - m2) * i2;
      float w1B = __expf(sc[i + 1] - m1) * i1, w2B = __expf(sce[i + 1] - m2) * i2;
      float w1C = __expf(sc[i + 2] - m1) * i1, w2C = __expf(sce[i + 2] - m2) * i2;
      float w1D = __expf(sc[i + 3] - m1) * i1, w2D = __expf(sce[i + 3] - m2) * i2;
      aH0 += w1A * bf2f((unsigned short)(hpA & 0xFFFFu)) + w1B * bf2f((unsigned short)(hpB & 0xFFFFu))
           + w1C * bf2f((unsigned short)(hpC & 0xFFFFu)) + w1D * bf2f((unsigned short)(hpD & 0xFFFFu));
      aH1 += w1A * bf2f((unsigned short)(hpA >> 16)) + w1B * bf2f((unsigned short)(hpB >> 16))
           + w1C * bf2f((unsigned short)(hpC >> 16)) + w1D * bf2f((unsigned short)(hpD >> 16));
      aE0 += w2A * bf2f((unsigned short)(epA & 0xFFFFu)) + w2B * bf2f((unsigned short)(epB & 0xFFFFu))
           + w2C * bf2f((unsigned short)(epC & 0xFFFFu)) + w2D * bf2f((unsigned short)(epD & 0xFFFFu));
      aE1 += w2A * bf2f((unsigned short)(epA >> 16)) + w2B * bf2f((unsigned short)(epB >> 16))
           + w2C * bf2f((unsigned short)(epC >> 16)) + w2D * bf2f((unsigned short)(epD >> 16));
    }
    for (; i < s1; ++i) {
      int nb = nr[i];
      int rr_ = er2[i];
      float w1 = __expf(sc[i] - m1) * i1;
      float w2 = __expf(sce[i] - m2) * i2;
      unsigned hp = *(const unsigned*)&hh[(long)nb * 128 + 2 * lane];
      unsigned ep = *(const unsigned*)&ejh[(long)rr_ * 128 + 2 * lane];
      aH0 += w1 * bf2f((unsigned short)(hp & 0xFFFFu));
      aH1 += w1 * bf2f((unsigned short)(hp >> 16));
      aE0 += w2 * bf2f((unsigned short)(ep & 0xFFFFu));
      aE1 += w2 * bf2f((unsigned short)(ep >> 16));
    }
  }
  _Float16* dstp = agg2 + ((long)dir * n + v) * 256;
  *(f16x2*)&dstp[2 * lane] = (f16x2){(_Float16)aH0, (_Float16)aH1};
  *(f16x2*)&dstp[128 + 2 * lane] = (f16x2){(_Float16)aE0, (_Float16)aE1};
}

// ---------------- K7: mix GEMM (fp16 MFMA) + LayerNorm + relu + residual ----------------
__global__ __launch_bounds__(256) void k_mix_ln(const _Float16* __restrict__ A,   // agg2 [2][M][256] f16
                                                const _Float16* __restrict__ McT, // [128][256] fp16
                                                const float* __restrict__ bias,   // bmix (x2)
                                                const float* __restrict__ h,
                                                const float* __restrict__ g,
                                                const float* __restrict__ bn,
                                                float* __restrict__ outp, int M) {
  __shared__ _Float16 Als[64][264];  // stride 528B = 132 dwords % 32 = 4 -> conflict-free
  int tid = threadIdx.x;
  int lane = tid & 63, w = tid >> 6;
  int kgrp = lane >> 4, sub = lane & 15;
  long mbase = (long)blockIdx.x * 64;
  const _Float16* A2 = A + (long)M * 256;
#pragma unroll
  for (int it = 0; it < 8; ++it) {
    int idx = tid + it * 256;      // 0..2047
    int r = idx >> 5, c8 = (idx & 31) * 8;
    long m = mbase + r;
    f16x8 hv = (f16x8){0, 0, 0, 0, 0, 0, 0, 0};
    if (m < M) {
      f16x8 v1 = *(const f16x8*)&A[m * 256 + c8];
      f16x8 v2 = *(const f16x8*)&A2[m * 256 + c8];
#pragma unroll
      for (int j = 0; j < 8; ++j) hv[j] = (_Float16)((float)v1[j] + (float)v2[j]);
    }
    *(f16x8*)&Als[r][c8] = hv;
  }
  __syncthreads();

  int arow = w * 16 + sub;
  f32x4 acc[8];
#pragma unroll
  for (int t = 0; t < 8; ++t) acc[t] = (f32x4){0.f, 0.f, 0.f, 0.f};
#pragma unroll
  for (int ks = 0; ks < 8; ++ks) {
    f16x8 a = *(const f16x8*)&Als[arow][ks * 32 + kgrp * 8];
#pragma unroll
    for (int t = 0; t < 8; ++t) {
      f16x8 b = *(const f16x8*)&McT[(t * 16 + sub) * 256 + ks * 32 + kgrp * 8];
      acc[t] = __builtin_amdgcn_mfma_f32_16x16x32_f16(a, b, acc[t], 0, 0, 0);
    }
  }

  float bb[8], gv[8], bv[8];
#pragma unroll
  for (int t = 0; t < 8; ++t) {
    int c = t * 16 + sub;
    bb[t] = 2.f * bias[c];
    gv[t] = g[c];
    bv[t] = bn[c];
  }

  // epilogue: lane owns rows w*16+kgrp*4+r, cols t*16+sub; row group = 16 sub-lanes
#pragma unroll
  for (int r = 0; r < 4; ++r) {
    int rl = w * 16 + kgrp * 4 + r;
    long m = mbase + rl;
    float x[8];
    float s = 0.f, q = 0.f;
#pragma unroll
    for (int t = 0; t < 8; ++t) {
      x[t] = acc[t][r] + bb[t];
      s += x[t];
      q += x[t] * x[t];
    }
#pragma unroll
    for (int mk = 1; mk < 16; mk <<= 1) {
      s += __shfl_xor(s, mk);
      q += __shfl_xor(q, mk);
    }
    float mu = s * (1.f / 128.f);
    float var = q * (1.f / 128.f) - mu * mu;
    float rstd = rsqrtf(var + 1e-5f);
    if (m < M) {
      const float* hp = h + m * 128;
#pragma unroll
      for (int t = 0; t < 8; ++t) {
        int c = t * 16 + sub;
        outp[m * 128 + c] = fmaxf((x[t] - mu) * rstd * gv[t] + bv[t], 0.f) + hp[c];
      }
    }
  }
}

extern "C" void kernel_launch(void* const* d_in, const int* in_sizes, int n_in,
                              void* d_out, int out_size, void* d_ws, size_t ws_size,
                              hipStream_t stream) {
  const float* h = (const float*)d_in[0];
  const float* e = (const float*)d_in[1];
  const int* src = (const int*)d_in[2];
  const int* dst = (const int*)d_in[3];
  const float* Wfc = (const float*)d_in[4];
  const float* Wfce = (const float*)d_in[5];
  const float* aat = (const float*)d_in[6];
  const float* aate = (const float*)d_in[7];
  const float* WB1 = (const float*)d_in[8];
  const float* bB1 = (const float*)d_in[9];
  const float* WB2 = (const float*)d_in[10];
  const float* bB2 = (const float*)d_in[11];
  const float* WB3 = (const float*)d_in[12];
  const float* bB3 = (const float*)d_in[13];
  const float* Wmix = (const float*)d_in[14];
  const float* bmix = (const float*)d_in[15];
  const float* lng = (const float*)d_in[16];
  const float* lnb = (const float*)d_in[17];
  int n = in_sizes[0] / 128;
  int E = in_sizes[1] / 128;

  float* hout = (float*)d_out;
  float* eout = (float*)d_out + (size_t)n * 128;

  char* w = (char*)d_ws;
  auto alloc = [&](size_t bytes) {
    void* p = w;
    w += (bytes + 255) / 256 * 256;
    return p;
  };
  unsigned short* B1hh = (unsigned short*)alloc((size_t)n * 128 * 2);
  unsigned short* B2hh = (unsigned short*)alloc((size_t)n * 128 * 2);
  _Float16* agg2 = (_Float16*)alloc((size_t)n * 512 * 2);
  float* zs1 = (float*)alloc((size_t)n * 4);
  float* zs3 = (float*)alloc((size_t)n * 4);
  float* ze1 = (float*)alloc((size_t)n * 4);
  float* ze3 = (float*)alloc((size_t)n * 4);
  float* zs2 = (float*)alloc((size_t)E * 4);
  float* ze2 = (float*)alloc((size_t)E * 4);
  float* sf = (float*)alloc((size_t)E * 4);
  float* sef = (float*)alloc((size_t)E * 4);
  float* sr = (float*)alloc((size_t)E * 4);
  float* ser = (float*)alloc((size_t)E * 4);
  float* cvec = (float*)alloc(768 * 4);
  _Float16* WT = (_Float16*)alloc(128 * 128 * 2);
  _Float16* W1T = (_Float16*)alloc(128 * 128 * 2);
  _Float16* W2T = (_Float16*)alloc(128 * 128 * 2);
  _Float16* McT = (_Float16*)alloc(128 * 256 * 2);
  int* offf = (int*)alloc((size_t)(n + 1) * 4);
  int* offr = (int*)alloc((size_t)(n + 1) * 4);
  size_t curpad = ((size_t)n * 4 + 255) / 256 * 256;
  int* curf = (int*)alloc((size_t)n * 4);
  int* curr = (int*)alloc((size_t)n * 4);
  int* eidf = (int*)alloc((size_t)E * 4);
  int* eidr = (int*)alloc((size_t)E * 4);
  int* posf = (int*)alloc((size_t)E * 4);
  int* nf = (int*)alloc((size_t)E * 4);
  int* nr = (int*)alloc((size_t)E * 4);
  int* er2 = (int*)alloc((size_t)E * 4);
  unsigned short* ejh = (unsigned short*)alloc((size_t)E * 128 * 2);
  unsigned short* hh = (unsigned short*)alloc((size_t)n * 128 * 2);

  hipMemsetAsync(curf, 0, curpad * 2, stream);  // curf + curr (adjacent)

  k_combine<<<262, 128, 0, stream>>>(Wfc, Wfce, Wmix, aat, aate, McT, cvec);
  k_wt3<<<192, 256, 0, stream>>>(WB3, WB1, WB2, WT, W1T, W2T);
  k_gemm_dual<<<(n + 63) / 64, 256, 0, stream>>>(h, W1T, bB1, W2T, bB2, cvec, B1hh, B2hh, hh,
                                                 zs1, zs3, ze1, ze3, n);
  k_hist<<<(E + 255) / 256, 256, 0, stream>>>(src, dst, curf, curr, E);
  k_scan<<<1, 1024, 0, stream>>>(curf, curr, offf, offr, n);
  hipMemsetAsync(curf, 0, curpad * 2, stream);
  k_fill<<<(E + 255) / 256, 256, 0, stream>>>(src, dst, offf, offr, curf, curr, eidf, eidr,
                                              posf, nullptr, E);
  k_edge<<<(E + 63) / 64, 256, 0, stream>>>(e, WT, bB3, B1hh, B2hh, src, dst, posf,
                                            cvec + 128, cvec + 512, eout, ejh, zs2, ze2, E);
  k_scores<<<(E + 255) / 256, 256, 0, stream>>>(src, dst, eidf, eidr, posf, zs1, zs2, zs3,
                                                ze1, ze2, ze3, sf, sef, sr, ser, nf, nr, er2, E);
  k_agg4<<<(2 * n + 3) / 4, 256, 0, stream>>>(offf, offr, nf, nr, er2, sf, sef, sr, ser,
                                              hh, ejh, agg2, n);
  k_mix_ln<<<(n + 63) / 64, 256, 0, stream>>>(agg2, McT, bmix, h, lng, lnb, hout, n);
}